// Round 1
// 222.877 us; speedup vs baseline: 1.0140x; 1.0140x over previous
//
#include <hip/hip_runtime.h>
#include <cstdint>
#include <cstddef>

// ---------------------------------------------------------------------------
// MHA: out = softmax(causal(mask((XWq)(XWk)^T/8))) (XWv) Wo + biases
// B=2, T=2048, D=1024, H=16, dk=64. bf16 MFMA, fp32 accumulate.
// R8: (1) gemm_body: 2-phase double-buffered staging (T3 minimum recipe) --
//     stage(k+1) issued BEFORE compute(k), ONE barrier per K-step; staging
//     latency hides under MFMA+ds_read. (2) Bijective XCD swizzle on both
//     GEMMs so A-panel-sharing blocks share an XCD L2 (panel re-fetch was
//     3.3x). (3) k0-invariant staging addresses hoisted out of the K-loop.
//     (4) attn: per-tile key masks precomputed into LDS (kills the dependent
//     global mask load per tile).
// ---------------------------------------------------------------------------

typedef __bf16 bf16x8 __attribute__((ext_vector_type(8)));
typedef float f32x4 __attribute__((ext_vector_type(4)));

#define MFMA(a, b, c) __builtin_amdgcn_mfma_f32_16x16x32_bf16((a), (b), (c), 0, 0, 0)

static constexpr int D_MODEL = 1024;
static constexpr int T_ = 2048;
static constexpr int M_TOK = 4096;   // B*T

__device__ __forceinline__ unsigned short f32_to_bf16(float f) {   // RNE
    union { float f; uint32_t u; } v; v.f = f;
    uint32_t u = v.u;
    uint32_t r = u + 0x7fffu + ((u >> 16) & 1u);
    return (unsigned short)(r >> 16);
}
__device__ __forceinline__ unsigned f32_to_bf16_fast(float f) {    // half-up
    union { float f; uint32_t u; } v; v.f = f;
    return (v.u + 0x8000u) >> 16;
}

typedef __attribute__((address_space(1))) void* as1_ptr;
typedef __attribute__((address_space(3))) void* as3_ptr;
__device__ __forceinline__ void gload_lds16(const void* g, void* l) {
    // lane's 16B land at (wave-uniform l) + lane*16
    __builtin_amdgcn_global_load_lds((as1_ptr)(void*)g, (as3_ptr)l, 16, 0, 0);
}

// sigma: actual key (within 64) -> storage index matching PV MFMA k-slots.
__device__ __forceinline__ int keyperm(int k) {
    return (k & 32) | ((k & 12) << 1) | ((k & 16) >> 2) | (k & 3);
}

// --------------------------- fused fp32 -> bf16 convert ---------------------
// dst (float4 units): q[0,1M) k[1M,2M) v[2M,3M) Wq Wk Wv Wo [3M..4M)
__global__ __launch_bounds__(256) void cvt_all(
    const float* __restrict__ q, const float* __restrict__ k,
    const float* __restrict__ v, const float* __restrict__ wq,
    const float* __restrict__ wk, const float* __restrict__ wv,
    const float* __restrict__ wo, ushort4* __restrict__ dst) {
    int i = blockIdx.x * blockDim.x + threadIdx.x;
    constexpr int R = 1 << 20;        // 1M float4 per token tensor
    const float* s;
    int idx;
    if (i < 3 * R) {
        s = (i < R) ? q : (i < 2 * R) ? k : v;
        idx = i & (R - 1);
    } else {
        int j = i - 3 * R;
        int w = j >> 18;
        s = (w == 0) ? wq : (w == 1) ? wk : (w == 2) ? wv : wo;
        idx = j & ((1 << 18) - 1);
    }
    float4 f = ((const float4*)s)[idx];
    ushort4 o;
    o.x = (unsigned short)f32_to_bf16(f.x); o.y = (unsigned short)f32_to_bf16(f.y);
    o.z = (unsigned short)f32_to_bf16(f.z); o.w = (unsigned short)f32_to_bf16(f.w);
    dst[i] = o;
}

// --------------------------- GEMM: C = A @ W^T + bias -----------------------
// Tile 128 x (NT16*32), BK=64, 4 waves 2x2, global_load_lds(16B), XOR swizzle.
// Double-buffered LDS, one barrier per K-step, prefetch issued over compute.
// MODE 0: bf16 row-major [M][1024] (Q,K; SWAPPED epilogue -> ushort4 stores).
// MODE 2: bf16 [B][H][64][Tperm] (V; UNswapped, t sigma-permuted per 64-blk).
// MODE 3: f32 row-major [M][1024] (SWAPPED -> float4 stores).
template<int MODE, int NT16>
__device__ __forceinline__ void gemm_body(
    const unsigned short* __restrict__ A, const unsigned short* __restrict__ W,
    const float* __restrict__ bias, void* __restrict__ outp,
    unsigned short* As, unsigned short* Ws, int bx, int by)
{
    constexpr bool SWAP = (MODE != 2);
    constexpr int ASZ = 128 * 64;           // ushorts per A buffer (16 KB)
    constexpr int WSZ = NT16 * 32 * 64;     // ushorts per W buffer
    const int tid = threadIdx.x;
    const int lane = tid & 63, wave = tid >> 6;
    const int wm = wave >> 1, wn = wave & 1;
    const int r16 = lane & 15, kg = lane >> 4;
    const int m_blk = by * 128, n_blk = bx * (NT16 * 32);

    // k0-invariant staging addresses (hoisted out of the K-loop)
    const unsigned short* Ap[4]; unsigned short* Al[4];
    #pragma unroll
    for (int j = 0; j < 4; ++j) {
        int si = j * 256 + tid;
        int row = si >> 3, cg = (si & 7) ^ (row & 7);
        Ap[j] = A + (size_t)(m_blk + row) * D_MODEL + cg * 8;
        Al[j] = As + (j * 256 + wave * 64) * 8;     // 16B units -> 8 ushorts
    }
    const unsigned short* Wp[NT16]; unsigned short* Wl[NT16];
    #pragma unroll
    for (int j = 0; j < NT16; ++j) {
        int si = j * 256 + tid;
        int row = si >> 3, cg = (si & 7) ^ (row & 7);
        Wp[j] = W + (size_t)(n_blk + row) * D_MODEL + cg * 8;
        Wl[j] = Ws + (j * 256 + wave * 64) * 8;
    }

    f32x4 acc[4][NT16];
    #pragma unroll
    for (int mt = 0; mt < 4; ++mt)
        #pragma unroll
        for (int nt = 0; nt < NT16; ++nt) acc[mt][nt] = (f32x4){0, 0, 0, 0};

    auto stage = [&](int bb, int k0) {
        #pragma unroll
        for (int j = 0; j < 4; ++j)
            gload_lds16(Ap[j] + k0, Al[j] + bb * ASZ);
        #pragma unroll
        for (int j = 0; j < NT16; ++j)
            gload_lds16(Wp[j] + k0, Wl[j] + bb * WSZ);
    };

    constexpr int NKS = D_MODEL / 64;       // 16
    stage(0, 0);
    for (int ks = 0; ks < NKS; ++ks) {
        __syncthreads();                    // drains vmcnt: stage(ks) landed;
                                            // all waves done reading buf ks^1
        if (ks + 1 < NKS) stage((ks + 1) & 1, (ks + 1) * 64);  // fly over compute
        const unsigned short* Asb = As + (ks & 1) * ASZ;
        const unsigned short* Wsb = Ws + (ks & 1) * WSZ;
        #pragma unroll
        for (int kc = 0; kc < 2; ++kc) {
            bf16x8 af[4], wf[NT16];
            #pragma unroll
            for (int mt = 0; mt < 4; ++mt) {
                int row = wm * 64 + mt * 16 + r16;
                af[mt] = *(const bf16x8*)(Asb + row * 64 + (((kc * 4 + kg) ^ (row & 7)) * 8));
            }
            #pragma unroll
            for (int nt = 0; nt < NT16; ++nt) {
                int row = wn * (NT16 * 16) + nt * 16 + r16;
                wf[nt] = *(const bf16x8*)(Wsb + row * 64 + (((kc * 4 + kg) ^ (row & 7)) * 8));
            }
            #pragma unroll
            for (int mt = 0; mt < 4; ++mt)
                #pragma unroll
                for (int nt = 0; nt < NT16; ++nt)
                    acc[mt][nt] = SWAP ? MFMA(wf[nt], af[mt], acc[mt][nt])
                                       : MFMA(af[mt], wf[nt], acc[mt][nt]);
        }
    }
    if (MODE == 2) {
        // UNswapped C/D: lane holds m = kg*4+r (t, consecutive), n = r16 fixed.
        #pragma unroll
        for (int nt = 0; nt < NT16; ++nt) {
            int n = n_blk + wn * (NT16 * 16) + nt * 16 + r16;
            float bn = bias[n];
            int hh = n >> 6, dki = n & 63;
            #pragma unroll
            for (int mt = 0; mt < 4; ++mt) {
                int m0 = m_blk + wm * 64 + mt * 16 + kg * 4;
                int mp = (m0 & ~63) | keyperm(m0 & 63);   // sigma within 64-blk
                int bb = mp >> 11, ti = mp & 2047;
                ushort4 pk;
                pk.x = f32_to_bf16(acc[mt][nt][0] + bn);
                pk.y = f32_to_bf16(acc[mt][nt][1] + bn);
                pk.z = f32_to_bf16(acc[mt][nt][2] + bn);
                pk.w = f32_to_bf16(acc[mt][nt][3] + bn);
                *(ushort4*)((unsigned short*)outp +
                    ((size_t)(bb * 16 + hh) * 64 + dki) * 2048 + ti) = pk;
            }
        }
    } else {
        // SWAPPED C/D: lane holds n = kg*4+r (consecutive), m = r16 fixed.
        #pragma unroll
        for (int nt = 0; nt < NT16; ++nt) {
            int n0 = n_blk + wn * (NT16 * 16) + nt * 16 + kg * 4;
            float4 bn4 = *(const float4*)(bias + n0);
            #pragma unroll
            for (int mt = 0; mt < 4; ++mt) {
                int m = m_blk + wm * 64 + mt * 16 + r16;
                if (MODE == 3) {
                    float4 st;
                    st.x = acc[mt][nt][0] + bn4.x; st.y = acc[mt][nt][1] + bn4.y;
                    st.z = acc[mt][nt][2] + bn4.z; st.w = acc[mt][nt][3] + bn4.w;
                    *(float4*)((float*)outp + (size_t)m * D_MODEL + n0) = st;
                } else {
                    ushort4 pk;
                    pk.x = f32_to_bf16(acc[mt][nt][0] + bn4.x);
                    pk.y = f32_to_bf16(acc[mt][nt][1] + bn4.y);
                    pk.z = f32_to_bf16(acc[mt][nt][2] + bn4.z);
                    pk.w = f32_to_bf16(acc[mt][nt][3] + bn4.w);
                    *(ushort4*)((unsigned short*)outp + (size_t)m * D_MODEL + n0) = pk;
                }
            }
        }
    }
}

__global__ __launch_bounds__(256) void gemm_qkv(
    const unsigned short* __restrict__ qb, const unsigned short* __restrict__ kb,
    const unsigned short* __restrict__ vb, const unsigned short* __restrict__ Wqb,
    const unsigned short* __restrict__ Wkb, const unsigned short* __restrict__ Wvb,
    const float* __restrict__ bq, const float* __restrict__ bk, const float* __restrict__ bv,
    unsigned short* __restrict__ Qhp, unsigned short* __restrict__ Khp,
    unsigned short* __restrict__ Vtp)
{
    __shared__ __align__(16) unsigned short As[2 * 128 * 64];   // 32 KB dbuf
    __shared__ __align__(16) unsigned short Ws[2 * 128 * 64];   // 32 KB dbuf
    // Bijective XCD swizzle (grid 8x32x3, nwg=768, 768%8==0): blocks with
    // flat%8==c land on XCD c; give each XCD a contiguous 96-work chunk so
    // the 8 bx-blocks sharing an A-panel (and one z's W) share an L2.
    int flat = blockIdx.x + (blockIdx.y << 3) + (blockIdx.z << 8);
    int w = (flat & 7) * 96 + (flat >> 3);
    int bx = w & 7, by = (w >> 3) & 31, z = w >> 8;
    const unsigned short* A = (z == 0) ? qb : (z == 1) ? kb : vb;
    const unsigned short* W = (z == 0) ? Wqb : (z == 1) ? Wkb : Wvb;
    const float* bias = (z == 0) ? bq : (z == 1) ? bk : bv;
    if (z < 2)
        gemm_body<0, 4>(A, W, bias, (z == 0) ? (void*)Qhp : (void*)Khp, As, Ws,
                        bx, by);
    else
        gemm_body<2, 4>(A, W, bias, (void*)Vtp, As, Ws, bx, by);
}

__global__ __launch_bounds__(256) void gemm_out(
    const unsigned short* __restrict__ ab, const unsigned short* __restrict__ Wob,
    const float* __restrict__ bo, float* __restrict__ outp)
{
    __shared__ __align__(16) unsigned short As[2 * 128 * 64];   // 32 KB dbuf
    __shared__ __align__(16) unsigned short Ws[2 * 64 * 64];    // 16 KB dbuf
    // Bijective XCD swizzle (grid 16x32, nwg=512): 64-work chunks per XCD ->
    // the 16 bx-blocks sharing an A-panel + full Wo stay in one L2 (~3 MB).
    int flat = blockIdx.x + (blockIdx.y << 4);
    int w = (flat & 7) * 64 + (flat >> 3);
    int bx = w & 15, by = w >> 4;
    gemm_body<3, 2>(ab, Wob, bo, (void*)outp, As, Ws, bx, by);
}

// --------------------------- flash attention --------------------------------
// One 64-q chunk per block (4 waves x 16 q); qc quadruple map balances causal
// work per CU; bh fastest-varying for XCD KV L2 locality (32 ≡ 0 mod 8 -> all
// y-blocks of a bh share an XCD already). Register-resident P (S^T =
// mfma(K,Q)); V stored key-permuted so PV B-frags are single b128 reads.
// Hot loop: all-ones-mask fast path (uniform branch), causal only on the
// diagonal tile; per-tile key masks precomputed into LDS (no dependent
// global load in the loop).
__global__ __launch_bounds__(256) void attn_fwd(
    const unsigned short* __restrict__ Qh, const unsigned short* __restrict__ Kh,
    const unsigned short* __restrict__ Vt, const int* __restrict__ mask,
    const int* __restrict__ causal_p, unsigned short* __restrict__ attnout)
{
    __shared__ __align__(16) unsigned short Ks[2][64 * 64];   // [key][dk] swz
    __shared__ __align__(16) unsigned short Vs[2][64 * 64];   // [dk][kperm] swz
    __shared__ unsigned long long kmS[32];                    // per-tile key mask

    const int tid = threadIdx.x;
    const int lane = tid & 63, wave = tid >> 6;
    const int bh = blockIdx.x;
    const int y = blockIdx.y, y0 = y & 7, j4 = y >> 3;
    const int qc = (j4 == 0) ? y0 : (j4 == 1) ? (15 - y0)
                 : (j4 == 2) ? (16 + y0) : (31 - y0);
    const int b = bh >> 4, h = bh & 15;
    const int causal = *causal_p;
    const int r16 = lane & 15, kg = lane >> 4;

    const int q0 = qc * 64 + wave * 16;

    const unsigned short* Qb = Qh + (size_t)b * T_ * D_MODEL + h * 64;
    const unsigned short* Kb = Kh + (size_t)b * T_ * D_MODEL + h * 64;
    const unsigned short* Vb = Vt + (size_t)bh * 64 * T_;
    const int* mb = mask + b * T_;

    // precompute per-tile 64-bit key masks into LDS (wave w: tiles w, w+4, ..)
    #pragma unroll
    for (int t = wave; t < 32; t += 4) {
        unsigned long long m = __ballot(mb[t * 64 + lane] != 0);
        if (lane == 0) kmS[t] = m;
    }

    // Q fragments (B-operand for S^T: lane holds Q[q0+r16][kg*8+j])
    bf16x8 qf0 = *(const bf16x8*)(Qb + (size_t)(q0 + r16) * D_MODEL + kg * 8);
    bf16x8 qf1 = *(const bf16x8*)(Qb + (size_t)(q0 + r16) * D_MODEL + 32 + kg * 8);

    float l = 0.f;                       // per-lane partial for q = r16
    f32x4 o[4];
    #pragma unroll
    for (int f = 0; f < 4; ++f) o[f] = (f32x4){0, 0, 0, 0};
    const float sc2 = 0.18033688011112042f;   // log2(e) / sqrt(64)
    const int lim = wave * 16 + r16;          // causal limit on diagonal tile

    const int nT = causal ? (qc + 1) : 32;

    auto stage = [&](int buf, int t) {
        int t0 = t * 64;
        #pragma unroll
        for (int j = 0; j < 2; ++j) {
            int si = j * 256 + tid;
            int row = si >> 3, cg = (si & 7) ^ (row & 7);
            gload_lds16(Kb + (size_t)(t0 + row) * D_MODEL + cg * 8,
                        (char*)Ks[buf] + (j * 256 + wave * 64) * 16);
            gload_lds16(Vb + (size_t)row * T_ + t0 + cg * 8,
                        (char*)Vs[buf] + (j * 256 + wave * 64) * 16);
        }
    };

    stage(0, 0);
    for (int t = 0; t < nT; ++t) {
        __syncthreads();              // stage(t) complete; kmS visible
        if (t + 1 < nT) stage((t + 1) & 1, t + 1);   // prefetch over compute
        const unsigned short* Kst = Ks[t & 1];
        const unsigned short* Vst = Vs[t & 1];
        const bool diag = causal && (t == qc);

        // key mask for this 64-key tile (wave-uniform, LDS broadcast)
        unsigned long long km = kmS[t];

        // ---- S^T = K Q^T ----
        f32x4 s[4];
        #pragma unroll
        for (int c = 0; c < 4; ++c) {
            int key = c * 16 + r16;
            bf16x8 kf0 = *(const bf16x8*)(Kst + key * 64 + ((kg ^ (key & 7)) * 8));
            bf16x8 kf1 = *(const bf16x8*)(Kst + key * 64 + (((4 + kg) ^ (key & 7)) * 8));
            f32x4 z = (f32x4){0, 0, 0, 0};
            z = MFMA(kf0, qf0, z);
            z = MFMA(kf1, qf1, z);
            s[c] = z;
        }

        // ---- exp2 (+ masks only when needed; uniform branch) ----
        float pv[4][4];
        if (!diag && km == ~0ull) {
            #pragma unroll
            for (int c = 0; c < 4; ++c)
                #pragma unroll
                for (int r = 0; r < 4; ++r) {
                    float e = __builtin_amdgcn_exp2f(s[c][r] * sc2);
                    pv[c][r] = e; l += e;
                }
        } else {
            #pragma unroll
            for (int c = 0; c < 4; ++c) {
                unsigned mc = (unsigned)(km >> (c * 16));
                #pragma unroll
                for (int r = 0; r < 4; ++r) {
                    int kbit = kg * 4 + r;
                    bool ok = ((mc >> kbit) & 1) && (!diag || (c * 16 + kbit <= lim));
                    float e = ok ? __builtin_amdgcn_exp2f(s[c][r] * sc2) : 0.f;
                    pv[c][r] = e; l += e;
                }
            }
        }

        // ---- pack into bf16x8 PV A-operands (sigma order) ----
        union pk_t { unsigned u[4]; bf16x8 v; };
        pk_t pa[2];
        #pragma unroll
        for (int c = 0; c < 4; ++c) {
            int half = (c & 1) * 2;
            pa[c >> 1].u[half]     = f32_to_bf16_fast(pv[c][0]) | (f32_to_bf16_fast(pv[c][1]) << 16);
            pa[c >> 1].u[half + 1] = f32_to_bf16_fast(pv[c][2]) | (f32_to_bf16_fast(pv[c][3]) << 16);
        }

        // ---- O += P V: single b128 V-frags (permuted key storage) ----
        #pragma unroll
        for (int f = 0; f < 4; ++f) {
            int row = f * 16 + r16;     // dk row in Vs
            int rx = row & 7;
            #pragma unroll
            for (int cp = 0; cp < 2; ++cp) {
                int g = cp * 4 + kg;    // storage granule = MFMA k-granule
                bf16x8 vf = *(const bf16x8*)(Vst + row * 64 + ((g ^ rx) * 8));
                o[f] = MFMA(pa[cp].v, vf, o[f]);
            }
        }
    }

    // ---- epilogue: reduce l across kg groups, normalize, store [B,T,D] ----
    l += __shfl_xor(l, 16, 64); l += __shfl_xor(l, 32, 64);
    float inv = (l > 0.f) ? 1.0f / l : 0.f;   // every lane: inv for q=r16
    #pragma unroll
    for (int r = 0; r < 4; ++r) {
        int ql = kg * 4 + r;                  // local q row to store
        float iv = __shfl(inv, ql, 64);
        size_t base = ((size_t)(b * T_ + q0 + ql)) * D_MODEL + h * 64;
        #pragma unroll
        for (int f = 0; f < 4; ++f)
            attnout[base + f * 16 + r16] = f32_to_bf16(o[f][r] * iv);
    }
}

// --------------------------- launch -----------------------------------------
extern "C" void kernel_launch(void* const* d_in, const int* in_sizes, int n_in,
                              void* d_out, int out_size, void* d_ws, size_t ws_size,
                              hipStream_t stream) {
    const float* q  = (const float*)d_in[0];
    const float* k  = (const float*)d_in[1];
    const float* v  = (const float*)d_in[2];
    const float* Wq = (const float*)d_in[3];
    const float* bq = (const float*)d_in[4];
    const float* Wk = (const float*)d_in[5];
    const float* bk = (const float*)d_in[6];
    const float* Wv = (const float*)d_in[7];
    const float* bv = (const float*)d_in[8];
    const float* Wo = (const float*)d_in[9];
    const float* bo = (const float*)d_in[10];
    const int* mask   = (const int*)d_in[11];
    const int* causal = (const int*)d_in[12];

    const size_t SZ_TOK = (size_t)M_TOK * D_MODEL;   // 4M elems
    const size_t SZ_W   = (size_t)D_MODEL * D_MODEL; // 1M elems

    unsigned short* qb  = (unsigned short*)d_ws;
    unsigned short* kb  = qb  + SZ_TOK;
    unsigned short* vb  = kb  + SZ_TOK;
    unsigned short* Wqb = vb  + SZ_TOK;
    unsigned short* Wkb = Wqb + SZ_W;
    unsigned short* Wvb = Wkb + SZ_W;
    unsigned short* Wob = Wvb + SZ_W;
    unsigned short* Qhp = Wob + SZ_W;
    unsigned short* Khp = Qhp + SZ_TOK;
    unsigned short* Vtp = Khp + SZ_TOK;
    unsigned short* ab  = Vtp + SZ_TOK;              // 64 MB total

    cvt_all<<<16384, 256, 0, stream>>>(q, k, v, Wq, Wk, Wv, Wo, (ushort4*)qb);

    gemm_qkv<<<dim3(D_MODEL / 128, M_TOK / 128, 3), 256, 0, stream>>>(
        qb, kb, vb, Wqb, Wkb, Wvb, bq, bk, bv, Qhp, Khp, Vtp);

    attn_fwd<<<dim3(32, 32), 256, 0, stream>>>(Qhp, Khp, Vtp, mask, causal, ab);

    gemm_out<<<dim3(D_MODEL / 64, M_TOK / 128), 256, 0, stream>>>(ab, Wob, bo,
                                                                  (float*)d_out);
}

// Round 2
// 220.784 us; speedup vs baseline: 1.0236x; 1.0095x over previous
//
#include <hip/hip_runtime.h>
#include <cstdint>
#include <cstddef>

// ---------------------------------------------------------------------------
// MHA: out = softmax(causal(mask((XWq)(XWk)^T/8))) (XWv) Wo + biases
// B=2, T=2048, D=1024, H=16, dk=64. bf16 MFMA, fp32 accumulate.
// R9: GEMMs -> BK=32, TRIPLE-buffered LDS (48 KB, 3 blocks/CU = grid's 3/CU),
//     depth-2 prefetch with raw s_barrier + counted s_waitcnt vmcnt(4)
//     (never 0 in the main loop): stage(ks+2) flies over TWO compute phases,
//     so the per-step barrier no longer drains the load queue. New bijective
//     granule swizzle g = p ^ ((row>>1)&3) for the 4-granule rows (2/bank,
//     free). gemm_out widened to 128-wide N (NT16=4). attn unchanged.
// ---------------------------------------------------------------------------

typedef __bf16 bf16x8 __attribute__((ext_vector_type(8)));
typedef float f32x4 __attribute__((ext_vector_type(4)));

#define MFMA(a, b, c) __builtin_amdgcn_mfma_f32_16x16x32_bf16((a), (b), (c), 0, 0, 0)

static constexpr int D_MODEL = 1024;
static constexpr int T_ = 2048;
static constexpr int M_TOK = 4096;   // B*T

__device__ __forceinline__ unsigned short f32_to_bf16(float f) {   // RNE
    union { float f; uint32_t u; } v; v.f = f;
    uint32_t u = v.u;
    uint32_t r = u + 0x7fffu + ((u >> 16) & 1u);
    return (unsigned short)(r >> 16);
}
__device__ __forceinline__ unsigned f32_to_bf16_fast(float f) {    // half-up
    union { float f; uint32_t u; } v; v.f = f;
    return (v.u + 0x8000u) >> 16;
}

typedef __attribute__((address_space(1))) void* as1_ptr;
typedef __attribute__((address_space(3))) void* as3_ptr;
__device__ __forceinline__ void gload_lds16(const void* g, void* l) {
    // lane's 16B land at (wave-uniform l) + lane*16
    __builtin_amdgcn_global_load_lds((as1_ptr)(void*)g, (as3_ptr)l, 16, 0, 0);
}

// sigma: actual key (within 64) -> storage index matching PV MFMA k-slots.
__device__ __forceinline__ int keyperm(int k) {
    return (k & 32) | ((k & 12) << 1) | ((k & 16) >> 2) | (k & 3);
}

// --------------------------- fused fp32 -> bf16 convert ---------------------
// dst (float4 units): q[0,1M) k[1M,2M) v[2M,3M) Wq Wk Wv Wo [3M..4M)
__global__ __launch_bounds__(256) void cvt_all(
    const float* __restrict__ q, const float* __restrict__ k,
    const float* __restrict__ v, const float* __restrict__ wq,
    const float* __restrict__ wk, const float* __restrict__ wv,
    const float* __restrict__ wo, ushort4* __restrict__ dst) {
    int i = blockIdx.x * blockDim.x + threadIdx.x;
    constexpr int R = 1 << 20;        // 1M float4 per token tensor
    const float* s;
    int idx;
    if (i < 3 * R) {
        s = (i < R) ? q : (i < 2 * R) ? k : v;
        idx = i & (R - 1);
    } else {
        int j = i - 3 * R;
        int w = j >> 18;
        s = (w == 0) ? wq : (w == 1) ? wk : (w == 2) ? wv : wo;
        idx = j & ((1 << 18) - 1);
    }
    float4 f = ((const float4*)s)[idx];
    ushort4 o;
    o.x = (unsigned short)f32_to_bf16(f.x); o.y = (unsigned short)f32_to_bf16(f.y);
    o.z = (unsigned short)f32_to_bf16(f.z); o.w = (unsigned short)f32_to_bf16(f.w);
    dst[i] = o;
}

// --------------------------- GEMM: C = A @ W^T + bias -----------------------
// Tile 128 x (NT16*32), BK=32, 4 waves 2x2, global_load_lds(16B).
// Triple-buffered LDS, raw s_barrier + counted vmcnt(4): two stages always
// in flight; the barrier never drains the load queue (main loop).
// Granule swizzle: row has 4 16B-granules; physical g = logical ^ ((row>>1)&3)
// -> a wave's 64 b128 reads map bijectively onto 64 slots (2/bank, free).
// MODE 0: bf16 row-major [M][1024] (Q,K; SWAPPED epilogue -> ushort4 stores).
// MODE 2: bf16 [B][H][64][Tperm] (V; UNswapped, t sigma-permuted per 64-blk).
// MODE 3: f32 row-major [M][1024] (SWAPPED -> float4 stores).
template<int MODE, int NT16>
__device__ __forceinline__ void gemm_body(
    const unsigned short* __restrict__ A, const unsigned short* __restrict__ W,
    const float* __restrict__ bias, void* __restrict__ outp,
    unsigned short* As, unsigned short* Ws, int bx, int by)
{
    constexpr bool SWAP = (MODE != 2);
    constexpr int BKE = 32;                     // K elems per step
    constexpr int ASZ = 128 * BKE;              // ushorts per A buffer (8 KB)
    constexpr int WSZ = NT16 * 32 * BKE;        // ushorts per W buffer
    constexpr int AL = ASZ / (256 * 8);         // gloads/thread for A (=2)
    constexpr int WL = WSZ / (256 * 8);         // gloads/thread for W (=2 @NT16=4)
    constexpr int NKS = D_MODEL / BKE;          // 32
    const int tid = threadIdx.x;
    const int lane = tid & 63, wave = tid >> 6;
    const int wm = wave >> 1, wn = wave & 1;
    const int r16 = lane & 15, kg = lane >> 4;
    const int m_blk = by * 128, n_blk = bx * (NT16 * 32);

    // hoisted staging addresses: source pre-swizzled, LDS dest linear
    const unsigned short* Ap[AL]; unsigned short* Albase[AL];
    #pragma unroll
    for (int j = 0; j < AL; ++j) {
        int si = j * 256 + tid;
        int row = si >> 2, p = si & 3, g = p ^ ((row >> 1) & 3);
        Ap[j] = A + (size_t)(m_blk + row) * D_MODEL + g * 8;
        Albase[j] = As + (j * 256 + wave * 64) * 8;   // wave-uniform base
    }
    const unsigned short* Wp[WL]; unsigned short* Wlbase[WL];
    #pragma unroll
    for (int j = 0; j < WL; ++j) {
        int si = j * 256 + tid;
        int row = si >> 2, p = si & 3, g = p ^ ((row >> 1) & 3);
        Wp[j] = W + (size_t)(n_blk + row) * D_MODEL + g * 8;
        Wlbase[j] = Ws + (j * 256 + wave * 64) * 8;
    }

    // hoisted (loop-invariant) ds_read offsets
    int aoff[4], woff[NT16];
    #pragma unroll
    for (int mt = 0; mt < 4; ++mt) {
        int row = wm * 64 + mt * 16 + r16;
        aoff[mt] = row * BKE + ((kg ^ ((row >> 1) & 3)) * 8);
    }
    #pragma unroll
    for (int nt = 0; nt < NT16; ++nt) {
        int row = wn * (NT16 * 16) + nt * 16 + r16;
        woff[nt] = row * BKE + ((kg ^ ((row >> 1) & 3)) * 8);
    }

    f32x4 acc[4][NT16];
    #pragma unroll
    for (int mt = 0; mt < 4; ++mt)
        #pragma unroll
        for (int nt = 0; nt < NT16; ++nt) acc[mt][nt] = (f32x4){0, 0, 0, 0};

    auto stage = [&](int bb, int k0) {
        #pragma unroll
        for (int j = 0; j < AL; ++j)
            gload_lds16(Ap[j] + k0, Albase[j] + bb * ASZ);
        #pragma unroll
        for (int j = 0; j < WL; ++j)
            gload_lds16(Wp[j] + k0, Wlbase[j] + bb * WSZ);
    };

    // prologue: two stages in flight
    stage(0, 0);
    stage(1, BKE);
    int cb = 0;                                 // compute buffer = ks % 3
    for (int ks = 0; ks < NKS; ++ks) {
        // wait ONLY for stage(ks) (issued 2 steps ago); stage(ks+1) stays in
        // flight across the barrier. Last iter: drain.
        if (ks + 1 < NKS) asm volatile("s_waitcnt vmcnt(4)" ::: "memory");
        else              asm volatile("s_waitcnt vmcnt(0)" ::: "memory");
        __builtin_amdgcn_s_barrier();           // raw: no compiler vmcnt drain
        __builtin_amdgcn_sched_barrier(0);      // ds_reads must not hoist above
        if (ks + 2 < NKS) {
            int sb = cb + 2; if (sb >= 3) sb -= 3;
            stage(sb, (ks + 2) * BKE);          // buf freed by compute(ks-1)
        }
        const unsigned short* Asb = As + cb * ASZ;
        const unsigned short* Wsb = Ws + cb * WSZ;
        bf16x8 af[4], wf[NT16];
        #pragma unroll
        for (int mt = 0; mt < 4; ++mt)
            af[mt] = *(const bf16x8*)(Asb + aoff[mt]);
        #pragma unroll
        for (int nt = 0; nt < NT16; ++nt)
            wf[nt] = *(const bf16x8*)(Wsb + woff[nt]);
        #pragma unroll
        for (int mt = 0; mt < 4; ++mt)
            #pragma unroll
            for (int nt = 0; nt < NT16; ++nt)
                acc[mt][nt] = SWAP ? MFMA(wf[nt], af[mt], acc[mt][nt])
                                   : MFMA(af[mt], wf[nt], acc[mt][nt]);
        cb = (cb == 2) ? 0 : cb + 1;
    }

    if (MODE == 2) {
        // UNswapped C/D: lane holds m = kg*4+r (t, consecutive), n = r16 fixed.
        #pragma unroll
        for (int nt = 0; nt < NT16; ++nt) {
            int n = n_blk + wn * (NT16 * 16) + nt * 16 + r16;
            float bn = bias[n];
            int hh = n >> 6, dki = n & 63;
            #pragma unroll
            for (int mt = 0; mt < 4; ++mt) {
                int m0 = m_blk + wm * 64 + mt * 16 + kg * 4;
                int mp = (m0 & ~63) | keyperm(m0 & 63);   // sigma within 64-blk
                int bb = mp >> 11, ti = mp & 2047;
                ushort4 pk;
                pk.x = f32_to_bf16(acc[mt][nt][0] + bn);
                pk.y = f32_to_bf16(acc[mt][nt][1] + bn);
                pk.z = f32_to_bf16(acc[mt][nt][2] + bn);
                pk.w = f32_to_bf16(acc[mt][nt][3] + bn);
                *(ushort4*)((unsigned short*)outp +
                    ((size_t)(bb * 16 + hh) * 64 + dki) * 2048 + ti) = pk;
            }
        }
    } else {
        // SWAPPED C/D: lane holds n = kg*4+r (consecutive), m = r16 fixed.
        #pragma unroll
        for (int nt = 0; nt < NT16; ++nt) {
            int n0 = n_blk + wn * (NT16 * 16) + nt * 16 + kg * 4;
            float4 bn4 = *(const float4*)(bias + n0);
            #pragma unroll
            for (int mt = 0; mt < 4; ++mt) {
                int m = m_blk + wm * 64 + mt * 16 + r16;
                if (MODE == 3) {
                    float4 st;
                    st.x = acc[mt][nt][0] + bn4.x; st.y = acc[mt][nt][1] + bn4.y;
                    st.z = acc[mt][nt][2] + bn4.z; st.w = acc[mt][nt][3] + bn4.w;
                    *(float4*)((float*)outp + (size_t)m * D_MODEL + n0) = st;
                } else {
                    ushort4 pk;
                    pk.x = f32_to_bf16(acc[mt][nt][0] + bn4.x);
                    pk.y = f32_to_bf16(acc[mt][nt][1] + bn4.y);
                    pk.z = f32_to_bf16(acc[mt][nt][2] + bn4.z);
                    pk.w = f32_to_bf16(acc[mt][nt][3] + bn4.w);
                    *(ushort4*)((unsigned short*)outp + (size_t)m * D_MODEL + n0) = pk;
                }
            }
        }
    }
}

__global__ __launch_bounds__(256) void gemm_qkv(
    const unsigned short* __restrict__ qb, const unsigned short* __restrict__ kb,
    const unsigned short* __restrict__ vb, const unsigned short* __restrict__ Wqb,
    const unsigned short* __restrict__ Wkb, const unsigned short* __restrict__ Wvb,
    const float* __restrict__ bq, const float* __restrict__ bk, const float* __restrict__ bv,
    unsigned short* __restrict__ Qhp, unsigned short* __restrict__ Khp,
    unsigned short* __restrict__ Vtp)
{
    __shared__ __align__(16) unsigned short As[3 * 128 * 32];   // 24 KB tbuf
    __shared__ __align__(16) unsigned short Ws[3 * 128 * 32];   // 24 KB tbuf
    // Bijective XCD swizzle (grid 8x32x3, nwg=768): contiguous 96-chunks/XCD.
    int flat = blockIdx.x + (blockIdx.y << 3) + (blockIdx.z << 8);
    int w = (flat & 7) * 96 + (flat >> 3);
    int bx = w & 7, by = (w >> 3) & 31, z = w >> 8;
    const unsigned short* A = (z == 0) ? qb : (z == 1) ? kb : vb;
    const unsigned short* W = (z == 0) ? Wqb : (z == 1) ? Wkb : Wvb;
    const float* bias = (z == 0) ? bq : (z == 1) ? bk : bv;
    if (z < 2)
        gemm_body<0, 4>(A, W, bias, (z == 0) ? (void*)Qhp : (void*)Khp, As, Ws,
                        bx, by);
    else
        gemm_body<2, 4>(A, W, bias, (void*)Vtp, As, Ws, bx, by);
}

__global__ __launch_bounds__(256) void gemm_out(
    const unsigned short* __restrict__ ab, const unsigned short* __restrict__ Wob,
    const float* __restrict__ bo, float* __restrict__ outp)
{
    __shared__ __align__(16) unsigned short As[3 * 128 * 32];   // 24 KB tbuf
    __shared__ __align__(16) unsigned short Ws[3 * 128 * 32];   // 24 KB tbuf
    // 128-wide N tile now: grid 8x32 = 256 blocks; bijective XCD swizzle
    // (32-chunks/XCD): A-panel (1 MB) + full Wo (2 MB) fit one L2.
    int flat = blockIdx.x + (blockIdx.y << 3);
    int w = (flat & 7) * 32 + (flat >> 3);
    int bx = w & 7, by = w >> 3;
    gemm_body<3, 4>(ab, Wob, bo, (void*)outp, As, Ws, bx, by);
}

// --------------------------- flash attention --------------------------------
// One 64-q chunk per block (4 waves x 16 q); qc quadruple map balances causal
// work per CU; bh fastest-varying for XCD KV L2 locality. Register-resident P
// (S^T = mfma(K,Q)); V stored key-permuted so PV B-frags are single b128
// reads. Hot loop: all-ones-mask fast path (uniform branch), causal only on
// the diagonal tile; per-tile key masks precomputed into LDS.
__global__ __launch_bounds__(256) void attn_fwd(
    const unsigned short* __restrict__ Qh, const unsigned short* __restrict__ Kh,
    const unsigned short* __restrict__ Vt, const int* __restrict__ mask,
    const int* __restrict__ causal_p, unsigned short* __restrict__ attnout)
{
    __shared__ __align__(16) unsigned short Ks[2][64 * 64];   // [key][dk] swz
    __shared__ __align__(16) unsigned short Vs[2][64 * 64];   // [dk][kperm] swz
    __shared__ unsigned long long kmS[32];                    // per-tile key mask

    const int tid = threadIdx.x;
    const int lane = tid & 63, wave = tid >> 6;
    const int bh = blockIdx.x;
    const int y = blockIdx.y, y0 = y & 7, j4 = y >> 3;
    const int qc = (j4 == 0) ? y0 : (j4 == 1) ? (15 - y0)
                 : (j4 == 2) ? (16 + y0) : (31 - y0);
    const int b = bh >> 4, h = bh & 15;
    const int causal = *causal_p;
    const int r16 = lane & 15, kg = lane >> 4;

    const int q0 = qc * 64 + wave * 16;

    const unsigned short* Qb = Qh + (size_t)b * T_ * D_MODEL + h * 64;
    const unsigned short* Kb = Kh + (size_t)b * T_ * D_MODEL + h * 64;
    const unsigned short* Vb = Vt + (size_t)bh * 64 * T_;
    const int* mb = mask + b * T_;

    // precompute per-tile 64-bit key masks into LDS (wave w: tiles w, w+4, ..)
    #pragma unroll
    for (int t = wave; t < 32; t += 4) {
        unsigned long long m = __ballot(mb[t * 64 + lane] != 0);
        if (lane == 0) kmS[t] = m;
    }

    // Q fragments (B-operand for S^T: lane holds Q[q0+r16][kg*8+j])
    bf16x8 qf0 = *(const bf16x8*)(Qb + (size_t)(q0 + r16) * D_MODEL + kg * 8);
    bf16x8 qf1 = *(const bf16x8*)(Qb + (size_t)(q0 + r16) * D_MODEL + 32 + kg * 8);

    float l = 0.f;                       // per-lane partial for q = r16
    f32x4 o[4];
    #pragma unroll
    for (int f = 0; f < 4; ++f) o[f] = (f32x4){0, 0, 0, 0};
    const float sc2 = 0.18033688011112042f;   // log2(e) / sqrt(64)
    const int lim = wave * 16 + r16;          // causal limit on diagonal tile

    const int nT = causal ? (qc + 1) : 32;

    auto stage = [&](int buf, int t) {
        int t0 = t * 64;
        #pragma unroll
        for (int j = 0; j < 2; ++j) {
            int si = j * 256 + tid;
            int row = si >> 3, cg = (si & 7) ^ (row & 7);
            gload_lds16(Kb + (size_t)(t0 + row) * D_MODEL + cg * 8,
                        (char*)Ks[buf] + (j * 256 + wave * 64) * 16);
            gload_lds16(Vb + (size_t)row * T_ + t0 + cg * 8,
                        (char*)Vs[buf] + (j * 256 + wave * 64) * 16);
        }
    };

    stage(0, 0);
    for (int t = 0; t < nT; ++t) {
        __syncthreads();              // stage(t) complete; kmS visible
        if (t + 1 < nT) stage((t + 1) & 1, t + 1);   // prefetch over compute
        const unsigned short* Kst = Ks[t & 1];
        const unsigned short* Vst = Vs[t & 1];
        const bool diag = causal && (t == qc);

        // key mask for this 64-key tile (wave-uniform, LDS broadcast)
        unsigned long long km = kmS[t];

        // ---- S^T = K Q^T ----
        f32x4 s[4];
        #pragma unroll
        for (int c = 0; c < 4; ++c) {
            int key = c * 16 + r16;
            bf16x8 kf0 = *(const bf16x8*)(Kst + key * 64 + ((kg ^ (key & 7)) * 8));
            bf16x8 kf1 = *(const bf16x8*)(Kst + key * 64 + (((4 + kg) ^ (key & 7)) * 8));
            f32x4 z = (f32x4){0, 0, 0, 0};
            z = MFMA(kf0, qf0, z);
            z = MFMA(kf1, qf1, z);
            s[c] = z;
        }

        // ---- exp2 (+ masks only when needed; uniform branch) ----
        float pv[4][4];
        if (!diag && km == ~0ull) {
            #pragma unroll
            for (int c = 0; c < 4; ++c)
                #pragma unroll
                for (int r = 0; r < 4; ++r) {
                    float e = __builtin_amdgcn_exp2f(s[c][r] * sc2);
                    pv[c][r] = e; l += e;
                }
        } else {
            #pragma unroll
            for (int c = 0; c < 4; ++c) {
                unsigned mc = (unsigned)(km >> (c * 16));
                #pragma unroll
                for (int r = 0; r < 4; ++r) {
                    int kbit = kg * 4 + r;
                    bool ok = ((mc >> kbit) & 1) && (!diag || (c * 16 + kbit <= lim));
                    float e = ok ? __builtin_amdgcn_exp2f(s[c][r] * sc2) : 0.f;
                    pv[c][r] = e; l += e;
                }
            }
        }

        // ---- pack into bf16x8 PV A-operands (sigma order) ----
        union pk_t { unsigned u[4]; bf16x8 v; };
        pk_t pa[2];
        #pragma unroll
        for (int c = 0; c < 4; ++c) {
            int half = (c & 1) * 2;
            pa[c >> 1].u[half]     = f32_to_bf16_fast(pv[c][0]) | (f32_to_bf16_fast(pv[c][1]) << 16);
            pa[c >> 1].u[half + 1] = f32_to_bf16_fast(pv[c][2]) | (f32_to_bf16_fast(pv[c][3]) << 16);
        }

        // ---- O += P V: single b128 V-frags (permuted key storage) ----
        #pragma unroll
        for (int f = 0; f < 4; ++f) {
            int row = f * 16 + r16;     // dk row in Vs
            int rx = row & 7;
            #pragma unroll
            for (int cp = 0; cp < 2; ++cp) {
                int g = cp * 4 + kg;    // storage granule = MFMA k-granule
                bf16x8 vf = *(const bf16x8*)(Vst + row * 64 + ((g ^ rx) * 8));
                o[f] = MFMA(pa[cp].v, vf, o[f]);
            }
        }
    }

    // ---- epilogue: reduce l across kg groups, normalize, store [B,T,D] ----
    l += __shfl_xor(l, 16, 64); l += __shfl_xor(l, 32, 64);
    float inv = (l > 0.f) ? 1.0f / l : 0.f;   // every lane: inv for q=r16
    #pragma unroll
    for (int r = 0; r < 4; ++r) {
        int ql = kg * 4 + r;                  // local q row to store
        float iv = __shfl(inv, ql, 64);
        size_t base = ((size_t)(b * T_ + q0 + ql)) * D_MODEL + h * 64;
        #pragma unroll
        for (int f = 0; f < 4; ++f)
            attnout[base + f * 16 + r16] = f32_to_bf16(o[f][r] * iv);
    }
}

// --------------------------- launch -----------------------------------------
extern "C" void kernel_launch(void* const* d_in, const int* in_sizes, int n_in,
                              void* d_out, int out_size, void* d_ws, size_t ws_size,
                              hipStream_t stream) {
    const float* q  = (const float*)d_in[0];
    const float* k  = (const float*)d_in[1];
    const float* v  = (const float*)d_in[2];
    const float* Wq = (const float*)d_in[3];
    const float* bq = (const float*)d_in[4];
    const float* Wk = (const float*)d_in[5];
    const float* bk = (const float*)d_in[6];
    const float* Wv = (const float*)d_in[7];
    const float* bv = (const float*)d_in[8];
    const float* Wo = (const float*)d_in[9];
    const float* bo = (const float*)d_in[10];
    const int* mask   = (const int*)d_in[11];
    const int* causal = (const int*)d_in[12];

    const size_t SZ_TOK = (size_t)M_TOK * D_MODEL;   // 4M elems
    const size_t SZ_W   = (size_t)D_MODEL * D_MODEL; // 1M elems

    unsigned short* qb  = (unsigned short*)d_ws;
    unsigned short* kb  = qb  + SZ_TOK;
    unsigned short* vb  = kb  + SZ_TOK;
    unsigned short* Wqb = vb  + SZ_TOK;
    unsigned short* Wkb = Wqb + SZ_W;
    unsigned short* Wvb = Wkb + SZ_W;
    unsigned short* Wob = Wvb + SZ_W;
    unsigned short* Qhp = Wob + SZ_W;
    unsigned short* Khp = Qhp + SZ_TOK;
    unsigned short* Vtp = Khp + SZ_TOK;
    unsigned short* ab  = Vtp + SZ_TOK;              // 64 MB total

    cvt_all<<<16384, 256, 0, stream>>>(q, k, v, Wq, Wk, Wv, Wo, (ushort4*)qb);

    gemm_qkv<<<dim3(D_MODEL / 128, M_TOK / 128, 3), 256, 0, stream>>>(
        qb, kb, vb, Wqb, Wkb, Wvb, bq, bk, bv, Qhp, Khp, Vtp);

    attn_fwd<<<dim3(32, 32), 256, 0, stream>>>(Qhp, Khp, Vtp, mask, causal, ab);

    gemm_out<<<dim3(D_MODEL / 128, M_TOK / 128), 256, 0, stream>>>(ab, Wob, bo,
                                                                   (float*)d_out);
}

// Round 4
// 218.877 us; speedup vs baseline: 1.0325x; 1.0087x over previous
//
#include <hip/hip_runtime.h>
#include <cstdint>
#include <cstddef>

// ---------------------------------------------------------------------------
// MHA: out = softmax(causal(mask((XWq)(XWk)^T/8))) (XWv) Wo + biases
// B=2, T=2048, D=1024, H=16, dk=64. bf16 MFMA, fp32 accumulate.
// R10 (attn VALU diet): (1) softmax scale log2(e)/8 folded into the Q
//     projection epilogue -> exp2(s) direct, no per-element mul. (2) softmax
//     denominator via MFMA ones-column (lacc = MFMA(pa, ones)): kills the
//     16-add serial chain per tile AND the epilogue shuffle reduce (denom
//     lands in o's exact lane/row slot; also numerator/denominator now use
//     identical bf16-rounded P). (3) attn staging addresses hoisted out of
//     the tile loop. (4) s_setprio(1) around attn MFMA clusters (T5).
//     GEMMs: R9 structure (BK=32 triple-buffer, counted vmcnt(4)) + oscale.
//     [R11 = R10 resubmit: round-3 bench died at container level (infra),
//      no kernel signal; code audited for hang hazards, none found.]
// ---------------------------------------------------------------------------

typedef __bf16 bf16x8 __attribute__((ext_vector_type(8)));
typedef float f32x4 __attribute__((ext_vector_type(4)));

#define MFMA(a, b, c) __builtin_amdgcn_mfma_f32_16x16x32_bf16((a), (b), (c), 0, 0, 0)

static constexpr int D_MODEL = 1024;
static constexpr int T_ = 2048;
static constexpr int M_TOK = 4096;   // B*T

__device__ __forceinline__ unsigned short f32_to_bf16(float f) {   // RNE
    union { float f; uint32_t u; } v; v.f = f;
    uint32_t u = v.u;
    uint32_t r = u + 0x7fffu + ((u >> 16) & 1u);
    return (unsigned short)(r >> 16);
}
__device__ __forceinline__ unsigned f32_to_bf16_fast(float f) {    // half-up
    union { float f; uint32_t u; } v; v.f = f;
    return (v.u + 0x8000u) >> 16;
}

typedef __attribute__((address_space(1))) void* as1_ptr;
typedef __attribute__((address_space(3))) void* as3_ptr;
__device__ __forceinline__ void gload_lds16(const void* g, void* l) {
    // lane's 16B land at (wave-uniform l) + lane*16
    __builtin_amdgcn_global_load_lds((as1_ptr)(void*)g, (as3_ptr)l, 16, 0, 0);
}

// sigma: actual key (within 64) -> storage index matching PV MFMA k-slots.
__device__ __forceinline__ int keyperm(int k) {
    return (k & 32) | ((k & 12) << 1) | ((k & 16) >> 2) | (k & 3);
}

// --------------------------- fused fp32 -> bf16 convert ---------------------
// dst (float4 units): q[0,1M) k[1M,2M) v[2M,3M) Wq Wk Wv Wo [3M..4M)
__global__ __launch_bounds__(256) void cvt_all(
    const float* __restrict__ q, const float* __restrict__ k,
    const float* __restrict__ v, const float* __restrict__ wq,
    const float* __restrict__ wk, const float* __restrict__ wv,
    const float* __restrict__ wo, ushort4* __restrict__ dst) {
    int i = blockIdx.x * blockDim.x + threadIdx.x;
    constexpr int R = 1 << 20;        // 1M float4 per token tensor
    const float* s;
    int idx;
    if (i < 3 * R) {
        s = (i < R) ? q : (i < 2 * R) ? k : v;
        idx = i & (R - 1);
    } else {
        int j = i - 3 * R;
        int w = j >> 18;
        s = (w == 0) ? wq : (w == 1) ? wk : (w == 2) ? wv : wo;
        idx = j & ((1 << 18) - 1);
    }
    float4 f = ((const float4*)s)[idx];
    ushort4 o;
    o.x = (unsigned short)f32_to_bf16(f.x); o.y = (unsigned short)f32_to_bf16(f.y);
    o.z = (unsigned short)f32_to_bf16(f.z); o.w = (unsigned short)f32_to_bf16(f.w);
    dst[i] = o;
}

// --------------------------- GEMM: C = A @ W^T + bias -----------------------
// Tile 128 x (NT16*32), BK=32, 4 waves 2x2, global_load_lds(16B).
// Triple-buffered LDS, raw s_barrier + counted vmcnt(4): two stages always
// in flight; the barrier never drains the load queue (main loop).
// Granule swizzle: row has 4 16B-granules; physical g = logical ^ ((row>>1)&3)
// -> a wave's 64 b128 reads map bijectively onto 64 slots (2/bank, free).
// MODE 0: bf16 row-major [M][1024] (Q,K; SWAPPED epilogue -> ushort4 stores).
// MODE 2: bf16 [B][H][64][Tperm] (V; UNswapped, t sigma-permuted per 64-blk).
// MODE 3: f32 row-major [M][1024] (SWAPPED -> float4 stores).
// oscale: multiplies (acc + bias) -- used to pre-scale Q by log2(e)/sqrt(dk).
template<int MODE, int NT16>
__device__ __forceinline__ void gemm_body(
    const unsigned short* __restrict__ A, const unsigned short* __restrict__ W,
    const float* __restrict__ bias, void* __restrict__ outp,
    unsigned short* As, unsigned short* Ws, int bx, int by, float oscale)
{
    constexpr bool SWAP = (MODE != 2);
    constexpr int BKE = 32;                     // K elems per step
    constexpr int ASZ = 128 * BKE;              // ushorts per A buffer (8 KB)
    constexpr int WSZ = NT16 * 32 * BKE;        // ushorts per W buffer
    constexpr int AL = ASZ / (256 * 8);         // gloads/thread for A (=2)
    constexpr int WL = WSZ / (256 * 8);         // gloads/thread for W (=2 @NT16=4)
    constexpr int NKS = D_MODEL / BKE;          // 32
    const int tid = threadIdx.x;
    const int lane = tid & 63, wave = tid >> 6;
    const int wm = wave >> 1, wn = wave & 1;
    const int r16 = lane & 15, kg = lane >> 4;
    const int m_blk = by * 128, n_blk = bx * (NT16 * 32);

    // hoisted staging addresses: source pre-swizzled, LDS dest linear
    const unsigned short* Ap[AL]; unsigned short* Albase[AL];
    #pragma unroll
    for (int j = 0; j < AL; ++j) {
        int si = j * 256 + tid;
        int row = si >> 2, p = si & 3, g = p ^ ((row >> 1) & 3);
        Ap[j] = A + (size_t)(m_blk + row) * D_MODEL + g * 8;
        Albase[j] = As + (j * 256 + wave * 64) * 8;   // wave-uniform base
    }
    const unsigned short* Wp[WL]; unsigned short* Wlbase[WL];
    #pragma unroll
    for (int j = 0; j < WL; ++j) {
        int si = j * 256 + tid;
        int row = si >> 2, p = si & 3, g = p ^ ((row >> 1) & 3);
        Wp[j] = W + (size_t)(n_blk + row) * D_MODEL + g * 8;
        Wlbase[j] = Ws + (j * 256 + wave * 64) * 8;
    }

    // hoisted (loop-invariant) ds_read offsets
    int aoff[4], woff[NT16];
    #pragma unroll
    for (int mt = 0; mt < 4; ++mt) {
        int row = wm * 64 + mt * 16 + r16;
        aoff[mt] = row * BKE + ((kg ^ ((row >> 1) & 3)) * 8);
    }
    #pragma unroll
    for (int nt = 0; nt < NT16; ++nt) {
        int row = wn * (NT16 * 16) + nt * 16 + r16;
        woff[nt] = row * BKE + ((kg ^ ((row >> 1) & 3)) * 8);
    }

    f32x4 acc[4][NT16];
    #pragma unroll
    for (int mt = 0; mt < 4; ++mt)
        #pragma unroll
        for (int nt = 0; nt < NT16; ++nt) acc[mt][nt] = (f32x4){0, 0, 0, 0};

    auto stage = [&](int bb, int k0) {
        #pragma unroll
        for (int j = 0; j < AL; ++j)
            gload_lds16(Ap[j] + k0, Albase[j] + bb * ASZ);
        #pragma unroll
        for (int j = 0; j < WL; ++j)
            gload_lds16(Wp[j] + k0, Wlbase[j] + bb * WSZ);
    };

    // prologue: two stages in flight
    stage(0, 0);
    stage(1, BKE);
    int cb = 0;                                 // compute buffer = ks % 3
    for (int ks = 0; ks < NKS; ++ks) {
        // wait ONLY for stage(ks) (issued 2 steps ago); stage(ks+1) stays in
        // flight across the barrier. Last iter: drain.
        if (ks + 1 < NKS) asm volatile("s_waitcnt vmcnt(4)" ::: "memory");
        else              asm volatile("s_waitcnt vmcnt(0)" ::: "memory");
        __builtin_amdgcn_s_barrier();           // raw: no compiler vmcnt drain
        __builtin_amdgcn_sched_barrier(0);      // ds_reads must not hoist above
        if (ks + 2 < NKS) {
            int sb = cb + 2; if (sb >= 3) sb -= 3;
            stage(sb, (ks + 2) * BKE);          // buf freed by compute(ks-1)
        }
        const unsigned short* Asb = As + cb * ASZ;
        const unsigned short* Wsb = Ws + cb * WSZ;
        bf16x8 af[4], wf[NT16];
        #pragma unroll
        for (int mt = 0; mt < 4; ++mt)
            af[mt] = *(const bf16x8*)(Asb + aoff[mt]);
        #pragma unroll
        for (int nt = 0; nt < NT16; ++nt)
            wf[nt] = *(const bf16x8*)(Wsb + woff[nt]);
        #pragma unroll
        for (int mt = 0; mt < 4; ++mt)
            #pragma unroll
            for (int nt = 0; nt < NT16; ++nt)
                acc[mt][nt] = SWAP ? MFMA(wf[nt], af[mt], acc[mt][nt])
                                   : MFMA(af[mt], wf[nt], acc[mt][nt]);
        cb = (cb == 2) ? 0 : cb + 1;
    }

    if (MODE == 2) {
        // UNswapped C/D: lane holds m = kg*4+r (t, consecutive), n = r16 fixed.
        #pragma unroll
        for (int nt = 0; nt < NT16; ++nt) {
            int n = n_blk + wn * (NT16 * 16) + nt * 16 + r16;
            float bn = bias[n];
            int hh = n >> 6, dki = n & 63;
            #pragma unroll
            for (int mt = 0; mt < 4; ++mt) {
                int m0 = m_blk + wm * 64 + mt * 16 + kg * 4;
                int mp = (m0 & ~63) | keyperm(m0 & 63);   // sigma within 64-blk
                int bb = mp >> 11, ti = mp & 2047;
                ushort4 pk;
                pk.x = f32_to_bf16((acc[mt][nt][0] + bn) * oscale);
                pk.y = f32_to_bf16((acc[mt][nt][1] + bn) * oscale);
                pk.z = f32_to_bf16((acc[mt][nt][2] + bn) * oscale);
                pk.w = f32_to_bf16((acc[mt][nt][3] + bn) * oscale);
                *(ushort4*)((unsigned short*)outp +
                    ((size_t)(bb * 16 + hh) * 64 + dki) * 2048 + ti) = pk;
            }
        }
    } else {
        // SWAPPED C/D: lane holds n = kg*4+r (consecutive), m = r16 fixed.
        #pragma unroll
        for (int nt = 0; nt < NT16; ++nt) {
            int n0 = n_blk + wn * (NT16 * 16) + nt * 16 + kg * 4;
            float4 bn4 = *(const float4*)(bias + n0);
            #pragma unroll
            for (int mt = 0; mt < 4; ++mt) {
                int m = m_blk + wm * 64 + mt * 16 + r16;
                if (MODE == 3) {
                    float4 st;
                    st.x = (acc[mt][nt][0] + bn4.x) * oscale;
                    st.y = (acc[mt][nt][1] + bn4.y) * oscale;
                    st.z = (acc[mt][nt][2] + bn4.z) * oscale;
                    st.w = (acc[mt][nt][3] + bn4.w) * oscale;
                    *(float4*)((float*)outp + (size_t)m * D_MODEL + n0) = st;
                } else {
                    ushort4 pk;
                    pk.x = f32_to_bf16((acc[mt][nt][0] + bn4.x) * oscale);
                    pk.y = f32_to_bf16((acc[mt][nt][1] + bn4.y) * oscale);
                    pk.z = f32_to_bf16((acc[mt][nt][2] + bn4.z) * oscale);
                    pk.w = f32_to_bf16((acc[mt][nt][3] + bn4.w) * oscale);
                    *(ushort4*)((unsigned short*)outp + (size_t)m * D_MODEL + n0) = pk;
                }
            }
        }
    }
}

__global__ __launch_bounds__(256) void gemm_qkv(
    const unsigned short* __restrict__ qb, const unsigned short* __restrict__ kb,
    const unsigned short* __restrict__ vb, const unsigned short* __restrict__ Wqb,
    const unsigned short* __restrict__ Wkb, const unsigned short* __restrict__ Wvb,
    const float* __restrict__ bq, const float* __restrict__ bk, const float* __restrict__ bv,
    unsigned short* __restrict__ Qhp, unsigned short* __restrict__ Khp,
    unsigned short* __restrict__ Vtp)
{
    __shared__ __align__(16) unsigned short As[3 * 128 * 32];   // 24 KB tbuf
    __shared__ __align__(16) unsigned short Ws[3 * 128 * 32];   // 24 KB tbuf
    // Bijective XCD swizzle (grid 8x32x3, nwg=768): contiguous 96-chunks/XCD.
    int flat = blockIdx.x + (blockIdx.y << 3) + (blockIdx.z << 8);
    int w = (flat & 7) * 96 + (flat >> 3);
    int bx = w & 7, by = (w >> 3) & 31, z = w >> 8;
    const unsigned short* A = (z == 0) ? qb : (z == 1) ? kb : vb;
    const unsigned short* W = (z == 0) ? Wqb : (z == 1) ? Wkb : Wvb;
    const float* bias = (z == 0) ? bq : (z == 1) ? bk : bv;
    // Q stored pre-scaled by log2(e)/sqrt(dk): attn computes exp2(s) direct.
    float osc = (z == 0) ? 0.18033688011112042f : 1.0f;
    if (z < 2)
        gemm_body<0, 4>(A, W, bias, (z == 0) ? (void*)Qhp : (void*)Khp, As, Ws,
                        bx, by, osc);
    else
        gemm_body<2, 4>(A, W, bias, (void*)Vtp, As, Ws, bx, by, 1.0f);
}

__global__ __launch_bounds__(256) void gemm_out(
    const unsigned short* __restrict__ ab, const unsigned short* __restrict__ Wob,
    const float* __restrict__ bo, float* __restrict__ outp)
{
    __shared__ __align__(16) unsigned short As[3 * 128 * 32];   // 24 KB tbuf
    __shared__ __align__(16) unsigned short Ws[3 * 128 * 32];   // 24 KB tbuf
    // 128-wide N tile: grid 8x32 = 256 blocks; bijective XCD swizzle
    // (32-chunks/XCD): A-panel (1 MB) + full Wo (2 MB) fit one L2.
    int flat = blockIdx.x + (blockIdx.y << 3);
    int w = (flat & 7) * 32 + (flat >> 3);
    int bx = w & 7, by = w >> 3;
    gemm_body<3, 4>(ab, Wob, bo, (void*)outp, As, Ws, bx, by, 1.0f);
}

// --------------------------- flash attention --------------------------------
// One 64-q chunk per block (4 waves x 16 q); qc quadruple map balances causal
// work per CU; bh fastest-varying for XCD KV L2 locality. Register-resident P
// (S^T = mfma(K,Q)); V stored key-permuted so PV B-frags are single b128
// reads. Q arrives pre-scaled by log2(e)/sqrt(dk) -> exp2 direct. Softmax
// denominator computed on the MATRIX pipe: lacc = MFMA(pa, ones) gives
// row-sums of bf16-rounded P in exactly o's lane/row slot (no VALU chain,
// no epilogue shuffles). Staging addresses hoisted; setprio around MFMA.
__global__ __launch_bounds__(256) void attn_fwd(
    const unsigned short* __restrict__ Qh, const unsigned short* __restrict__ Kh,
    const unsigned short* __restrict__ Vt, const int* __restrict__ mask,
    const int* __restrict__ causal_p, unsigned short* __restrict__ attnout)
{
    __shared__ __align__(16) unsigned short Ks[2][64 * 64];   // [key][dk] swz
    __shared__ __align__(16) unsigned short Vs[2][64 * 64];   // [dk][kperm] swz
    __shared__ unsigned long long kmS[32];                    // per-tile key mask

    const int tid = threadIdx.x;
    const int lane = tid & 63, wave = tid >> 6;
    const int bh = blockIdx.x;
    const int y = blockIdx.y, y0 = y & 7, j4 = y >> 3;
    const int qc = (j4 == 0) ? y0 : (j4 == 1) ? (15 - y0)
                 : (j4 == 2) ? (16 + y0) : (31 - y0);
    const int b = bh >> 4, h = bh & 15;
    const int causal = *causal_p;
    const int r16 = lane & 15, kg = lane >> 4;

    const int q0 = qc * 64 + wave * 16;

    const unsigned short* Qb = Qh + (size_t)b * T_ * D_MODEL + h * 64;
    const unsigned short* Kb = Kh + (size_t)b * T_ * D_MODEL + h * 64;
    const unsigned short* Vb = Vt + (size_t)bh * 64 * T_;
    const int* mb = mask + b * T_;

    // precompute per-tile 64-bit key masks into LDS (wave w: tiles w, w+4, ..)
    for (int t = wave; t < 32; t += 4) {
        unsigned long long m = __ballot(mb[t * 64 + lane] != 0);
        if (lane == 0) kmS[t] = m;
    }

    // Q fragments (B-operand for S^T: lane holds Q[q0+r16][kg*8+j])
    bf16x8 qf0 = *(const bf16x8*)(Qb + (size_t)(q0 + r16) * D_MODEL + kg * 8);
    bf16x8 qf1 = *(const bf16x8*)(Qb + (size_t)(q0 + r16) * D_MODEL + 32 + kg * 8);

    // all-ones B-frag for the denominator MFMA
    union { unsigned u[4]; bf16x8 v; } onef;
    onef.u[0] = onef.u[1] = onef.u[2] = onef.u[3] = 0x3f803f80u;

    f32x4 lacc = (f32x4){0, 0, 0, 0};    // denom: lacc[r] = l for q = kg*4+r
    f32x4 o[4];
    #pragma unroll
    for (int f = 0; f < 4; ++f) o[f] = (f32x4){0, 0, 0, 0};
    const int lim = wave * 16 + r16;          // causal limit on diagonal tile

    const int nT = causal ? (qc + 1) : 32;

    // hoisted staging addresses (tile t adds t*64 rows on K / t*64 cols on V)
    const unsigned short* Kp[2]; const unsigned short* Vp[2];
    char* Kl[2]; char* Vl[2];
    #pragma unroll
    for (int j = 0; j < 2; ++j) {
        int si = j * 256 + tid;
        int row = si >> 3, cg = (si & 7) ^ (row & 7);
        Kp[j] = Kb + (size_t)row * D_MODEL + cg * 8;
        Vp[j] = Vb + (size_t)row * T_ + cg * 8;
        Kl[j] = (char*)Ks[0] + (j * 256 + wave * 64) * 16;
        Vl[j] = (char*)Vs[0] + (j * 256 + wave * 64) * 16;
    }
    auto stage = [&](int buf, int t) {
        #pragma unroll
        for (int j = 0; j < 2; ++j) {
            gload_lds16(Kp[j] + ((size_t)t << 16), Kl[j] + buf * 8192);  // t*64*1024
            gload_lds16(Vp[j] + (t << 6),          Vl[j] + buf * 8192);  // t*64
        }
    };

    stage(0, 0);
    for (int t = 0; t < nT; ++t) {
        __syncthreads();              // stage(t) complete; kmS visible
        if (t + 1 < nT) stage((t + 1) & 1, t + 1);   // prefetch over compute
        const unsigned short* Kst = Ks[t & 1];
        const unsigned short* Vst = Vs[t & 1];
        const bool diag = causal && (t == qc);

        // key mask for this 64-key tile (wave-uniform, LDS broadcast)
        unsigned long long km = kmS[t];

        // ---- S^T = K Q^T ----
        f32x4 s[4];
        __builtin_amdgcn_s_setprio(1);
        #pragma unroll
        for (int c = 0; c < 4; ++c) {
            int key = c * 16 + r16;
            bf16x8 kf0 = *(const bf16x8*)(Kst + key * 64 + ((kg ^ (key & 7)) * 8));
            bf16x8 kf1 = *(const bf16x8*)(Kst + key * 64 + (((4 + kg) ^ (key & 7)) * 8));
            f32x4 z = (f32x4){0, 0, 0, 0};
            z = MFMA(kf0, qf0, z);
            z = MFMA(kf1, qf1, z);
            s[c] = z;
        }
        __builtin_amdgcn_s_setprio(0);

        // ---- exp2 (Q pre-scaled; masks only when needed; uniform branch) ----
        float pv[4][4];
        if (!diag && km == ~0ull) {
            #pragma unroll
            for (int c = 0; c < 4; ++c)
                #pragma unroll
                for (int r = 0; r < 4; ++r)
                    pv[c][r] = __builtin_amdgcn_exp2f(s[c][r]);
        } else {
            #pragma unroll
            for (int c = 0; c < 4; ++c) {
                unsigned mc = (unsigned)(km >> (c * 16));
                #pragma unroll
                for (int r = 0; r < 4; ++r) {
                    int kbit = kg * 4 + r;
                    bool ok = ((mc >> kbit) & 1) && (!diag || (c * 16 + kbit <= lim));
                    pv[c][r] = ok ? __builtin_amdgcn_exp2f(s[c][r]) : 0.f;
                }
            }
        }

        // ---- pack into bf16x8 PV A-operands (sigma order) ----
        union pk_t { unsigned u[4]; bf16x8 v; };
        pk_t pa[2];
        #pragma unroll
        for (int c = 0; c < 4; ++c) {
            int half = (c & 1) * 2;
            pa[c >> 1].u[half]     = f32_to_bf16_fast(pv[c][0]) | (f32_to_bf16_fast(pv[c][1]) << 16);
            pa[c >> 1].u[half + 1] = f32_to_bf16_fast(pv[c][2]) | (f32_to_bf16_fast(pv[c][3]) << 16);
        }

        // ---- O += P V; denom += P 1 (matrix pipe, layout-proof) ----
        __builtin_amdgcn_s_setprio(1);
        lacc = MFMA(pa[0].v, onef.v, lacc);
        lacc = MFMA(pa[1].v, onef.v, lacc);
        #pragma unroll
        for (int f = 0; f < 4; ++f) {
            int row = f * 16 + r16;     // dk row in Vs
            int rx = row & 7;
            #pragma unroll
            for (int cp = 0; cp < 2; ++cp) {
                int g = cp * 4 + kg;    // storage granule = MFMA k-granule
                bf16x8 vf = *(const bf16x8*)(Vst + row * 64 + ((g ^ rx) * 8));
                o[f] = MFMA(pa[cp].v, vf, o[f]);
            }
        }
        __builtin_amdgcn_s_setprio(0);
    }

    // ---- epilogue: normalize with lane-local denom, store [B,T,D] ----
    #pragma unroll
    for (int r = 0; r < 4; ++r) {
        float iv = (lacc[r] > 0.f) ? 1.0f / lacc[r] : 0.f;
        size_t base = ((size_t)(b * T_ + q0 + kg * 4 + r)) * D_MODEL + h * 64;
        #pragma unroll
        for (int f = 0; f < 4; ++f)
            attnout[base + f * 16 + r16] = f32_to_bf16(o[f][r] * iv);
    }
}

// --------------------------- launch -----------------------------------------
extern "C" void kernel_launch(void* const* d_in, const int* in_sizes, int n_in,
                              void* d_out, int out_size, void* d_ws, size_t ws_size,
                              hipStream_t stream) {
    const float* q  = (const float*)d_in[0];
    const float* k  = (const float*)d_in[1];
    const float* v  = (const float*)d_in[2];
    const float* Wq = (const float*)d_in[3];
    const float* bq = (const float*)d_in[4];
    const float* Wk = (const float*)d_in[5];
    const float* bk = (const float*)d_in[6];
    const float* Wv = (const float*)d_in[7];
    const float* bv = (const float*)d_in[8];
    const float* Wo = (const float*)d_in[9];
    const float* bo = (const float*)d_in[10];
    const int* mask   = (const int*)d_in[11];
    const int* causal = (const int*)d_in[12];

    const size_t SZ_TOK = (size_t)M_TOK * D_MODEL;   // 4M elems
    const size_t SZ_W   = (size_t)D_MODEL * D_MODEL; // 1M elems

    unsigned short* qb  = (unsigned short*)d_ws;
    unsigned short* kb  = qb  + SZ_TOK;
    unsigned short* vb  = kb  + SZ_TOK;
    unsigned short* Wqb = vb  + SZ_TOK;
    unsigned short* Wkb = Wqb + SZ_W;
    unsigned short* Wvb = Wkb + SZ_W;
    unsigned short* Wob = Wvb + SZ_W;
    unsigned short* Qhp = Wob + SZ_W;
    unsigned short* Khp = Qhp + SZ_TOK;
    unsigned short* Vtp = Khp + SZ_TOK;
    unsigned short* ab  = Vtp + SZ_TOK;              // 64 MB total

    cvt_all<<<16384, 256, 0, stream>>>(q, k, v, Wq, Wk, Wv, Wo, (ushort4*)qb);

    gemm_qkv<<<dim3(D_MODEL / 128, M_TOK / 128, 3), 256, 0, stream>>>(
        qb, kb, vb, Wqb, Wkb, Wvb, bq, bk, bv, Qhp, Khp, Vtp);

    attn_fwd<<<dim3(32, 32), 256, 0, stream>>>(Qhp, Khp, Vtp, mask, causal, ab);

    gemm_out<<<dim3(D_MODEL / 128, M_TOK / 128), 256, 0, stream>>>(ab, Wob, bo,
                                                                   (float*)d_out);
}

// Round 5
// 217.709 us; speedup vs baseline: 1.0381x; 1.0054x over previous
//
#include <hip/hip_runtime.h>
#include <cstdint>
#include <cstddef>

// ---------------------------------------------------------------------------
// MHA: out = softmax(causal(mask((XWq)(XWk)^T/8))) (XWv) Wo + biases
// B=2, T=2048, D=1024, H=16, dk=64. bf16 MFMA, fp32 accumulate.
// R12 (attn stall fix; GEMMs frozen at R9/R10 structure):
//   attn was stall-bound: per-tile interval ~1.7-4kcy vs ~600cy pipe work;
//   __syncthreads drained the depth-1 KV prefetch every tile, and the
//   longest causal blocks (qc 24-31) dispatched LAST (pure serial tail).
//   (1) K/V triple-buffered (48.4 KB, 3 blocks/CU), raw s_barrier +
//       counted s_waitcnt vmcnt(4): stage(t+2) in flight across barriers,
//       never drained in the main loop (R9's verified GEMM pattern).
//   (2) Longest-first qc map {31-y0,16+y0,15-y0,y0}: per-CU quadruple still
//       66 tiles, but 25-32-tile blocks start at t=0; short blocks backfill.
//   R10 carried: Q pre-scaled by log2(e)/8 (exp2 direct), denominator on
//   the matrix pipe (lacc=MFMA(pa,ones)), hoisted staging addrs, setprio.
// ---------------------------------------------------------------------------

typedef __bf16 bf16x8 __attribute__((ext_vector_type(8)));
typedef float f32x4 __attribute__((ext_vector_type(4)));

#define MFMA(a, b, c) __builtin_amdgcn_mfma_f32_16x16x32_bf16((a), (b), (c), 0, 0, 0)

static constexpr int D_MODEL = 1024;
static constexpr int T_ = 2048;
static constexpr int M_TOK = 4096;   // B*T

__device__ __forceinline__ unsigned short f32_to_bf16(float f) {   // RNE
    union { float f; uint32_t u; } v; v.f = f;
    uint32_t u = v.u;
    uint32_t r = u + 0x7fffu + ((u >> 16) & 1u);
    return (unsigned short)(r >> 16);
}
__device__ __forceinline__ unsigned f32_to_bf16_fast(float f) {    // half-up
    union { float f; uint32_t u; } v; v.f = f;
    return (v.u + 0x8000u) >> 16;
}

typedef __attribute__((address_space(1))) void* as1_ptr;
typedef __attribute__((address_space(3))) void* as3_ptr;
__device__ __forceinline__ void gload_lds16(const void* g, void* l) {
    // lane's 16B land at (wave-uniform l) + lane*16
    __builtin_amdgcn_global_load_lds((as1_ptr)(void*)g, (as3_ptr)l, 16, 0, 0);
}

// sigma: actual key (within 64) -> storage index matching PV MFMA k-slots.
__device__ __forceinline__ int keyperm(int k) {
    return (k & 32) | ((k & 12) << 1) | ((k & 16) >> 2) | (k & 3);
}

// --------------------------- fused fp32 -> bf16 convert ---------------------
// dst (float4 units): q[0,1M) k[1M,2M) v[2M,3M) Wq Wk Wv Wo [3M..4M)
__global__ __launch_bounds__(256) void cvt_all(
    const float* __restrict__ q, const float* __restrict__ k,
    const float* __restrict__ v, const float* __restrict__ wq,
    const float* __restrict__ wk, const float* __restrict__ wv,
    const float* __restrict__ wo, ushort4* __restrict__ dst) {
    int i = blockIdx.x * blockDim.x + threadIdx.x;
    constexpr int R = 1 << 20;        // 1M float4 per token tensor
    const float* s;
    int idx;
    if (i < 3 * R) {
        s = (i < R) ? q : (i < 2 * R) ? k : v;
        idx = i & (R - 1);
    } else {
        int j = i - 3 * R;
        int w = j >> 18;
        s = (w == 0) ? wq : (w == 1) ? wk : (w == 2) ? wv : wo;
        idx = j & ((1 << 18) - 1);
    }
    float4 f = ((const float4*)s)[idx];
    ushort4 o;
    o.x = (unsigned short)f32_to_bf16(f.x); o.y = (unsigned short)f32_to_bf16(f.y);
    o.z = (unsigned short)f32_to_bf16(f.z); o.w = (unsigned short)f32_to_bf16(f.w);
    dst[i] = o;
}

// --------------------------- GEMM: C = A @ W^T + bias -----------------------
// Tile 128 x (NT16*32), BK=32, 4 waves 2x2, global_load_lds(16B).
// Triple-buffered LDS, raw s_barrier + counted vmcnt(4): two stages always
// in flight; the barrier never drains the load queue (main loop).
// Granule swizzle: row has 4 16B-granules; physical g = logical ^ ((row>>1)&3)
// -> a wave's 64 b128 reads map bijectively onto 64 slots (2/bank, free).
// MODE 0: bf16 row-major [M][1024] (Q,K; SWAPPED epilogue -> ushort4 stores).
// MODE 2: bf16 [B][H][64][Tperm] (V; UNswapped, t sigma-permuted per 64-blk).
// MODE 3: f32 row-major [M][1024] (SWAPPED -> float4 stores).
// oscale: multiplies (acc + bias) -- used to pre-scale Q by log2(e)/sqrt(dk).
template<int MODE, int NT16>
__device__ __forceinline__ void gemm_body(
    const unsigned short* __restrict__ A, const unsigned short* __restrict__ W,
    const float* __restrict__ bias, void* __restrict__ outp,
    unsigned short* As, unsigned short* Ws, int bx, int by, float oscale)
{
    constexpr bool SWAP = (MODE != 2);
    constexpr int BKE = 32;                     // K elems per step
    constexpr int ASZ = 128 * BKE;              // ushorts per A buffer (8 KB)
    constexpr int WSZ = NT16 * 32 * BKE;        // ushorts per W buffer
    constexpr int AL = ASZ / (256 * 8);         // gloads/thread for A (=2)
    constexpr int WL = WSZ / (256 * 8);         // gloads/thread for W (=2 @NT16=4)
    constexpr int NKS = D_MODEL / BKE;          // 32
    const int tid = threadIdx.x;
    const int lane = tid & 63, wave = tid >> 6;
    const int wm = wave >> 1, wn = wave & 1;
    const int r16 = lane & 15, kg = lane >> 4;
    const int m_blk = by * 128, n_blk = bx * (NT16 * 32);

    // hoisted staging addresses: source pre-swizzled, LDS dest linear
    const unsigned short* Ap[AL]; unsigned short* Albase[AL];
    #pragma unroll
    for (int j = 0; j < AL; ++j) {
        int si = j * 256 + tid;
        int row = si >> 2, p = si & 3, g = p ^ ((row >> 1) & 3);
        Ap[j] = A + (size_t)(m_blk + row) * D_MODEL + g * 8;
        Albase[j] = As + (j * 256 + wave * 64) * 8;   // wave-uniform base
    }
    const unsigned short* Wp[WL]; unsigned short* Wlbase[WL];
    #pragma unroll
    for (int j = 0; j < WL; ++j) {
        int si = j * 256 + tid;
        int row = si >> 2, p = si & 3, g = p ^ ((row >> 1) & 3);
        Wp[j] = W + (size_t)(n_blk + row) * D_MODEL + g * 8;
        Wlbase[j] = Ws + (j * 256 + wave * 64) * 8;
    }

    // hoisted (loop-invariant) ds_read offsets
    int aoff[4], woff[NT16];
    #pragma unroll
    for (int mt = 0; mt < 4; ++mt) {
        int row = wm * 64 + mt * 16 + r16;
        aoff[mt] = row * BKE + ((kg ^ ((row >> 1) & 3)) * 8);
    }
    #pragma unroll
    for (int nt = 0; nt < NT16; ++nt) {
        int row = wn * (NT16 * 16) + nt * 16 + r16;
        woff[nt] = row * BKE + ((kg ^ ((row >> 1) & 3)) * 8);
    }

    f32x4 acc[4][NT16];
    #pragma unroll
    for (int mt = 0; mt < 4; ++mt)
        #pragma unroll
        for (int nt = 0; nt < NT16; ++nt) acc[mt][nt] = (f32x4){0, 0, 0, 0};

    auto stage = [&](int bb, int k0) {
        #pragma unroll
        for (int j = 0; j < AL; ++j)
            gload_lds16(Ap[j] + k0, Albase[j] + bb * ASZ);
        #pragma unroll
        for (int j = 0; j < WL; ++j)
            gload_lds16(Wp[j] + k0, Wlbase[j] + bb * WSZ);
    };

    // prologue: two stages in flight
    stage(0, 0);
    stage(1, BKE);
    int cb = 0;                                 // compute buffer = ks % 3
    for (int ks = 0; ks < NKS; ++ks) {
        // wait ONLY for stage(ks) (issued 2 steps ago); stage(ks+1) stays in
        // flight across the barrier. Last iter: drain.
        if (ks + 1 < NKS) asm volatile("s_waitcnt vmcnt(4)" ::: "memory");
        else              asm volatile("s_waitcnt vmcnt(0)" ::: "memory");
        __builtin_amdgcn_s_barrier();           // raw: no compiler vmcnt drain
        __builtin_amdgcn_sched_barrier(0);      // ds_reads must not hoist above
        if (ks + 2 < NKS) {
            int sb = cb + 2; if (sb >= 3) sb -= 3;
            stage(sb, (ks + 2) * BKE);          // buf freed by compute(ks-1)
        }
        const unsigned short* Asb = As + cb * ASZ;
        const unsigned short* Wsb = Ws + cb * WSZ;
        bf16x8 af[4], wf[NT16];
        #pragma unroll
        for (int mt = 0; mt < 4; ++mt)
            af[mt] = *(const bf16x8*)(Asb + aoff[mt]);
        #pragma unroll
        for (int nt = 0; nt < NT16; ++nt)
            wf[nt] = *(const bf16x8*)(Wsb + woff[nt]);
        #pragma unroll
        for (int mt = 0; mt < 4; ++mt)
            #pragma unroll
            for (int nt = 0; nt < NT16; ++nt)
                acc[mt][nt] = SWAP ? MFMA(wf[nt], af[mt], acc[mt][nt])
                                   : MFMA(af[mt], wf[nt], acc[mt][nt]);
        cb = (cb == 2) ? 0 : cb + 1;
    }

    if (MODE == 2) {
        // UNswapped C/D: lane holds m = kg*4+r (t, consecutive), n = r16 fixed.
        #pragma unroll
        for (int nt = 0; nt < NT16; ++nt) {
            int n = n_blk + wn * (NT16 * 16) + nt * 16 + r16;
            float bn = bias[n];
            int hh = n >> 6, dki = n & 63;
            #pragma unroll
            for (int mt = 0; mt < 4; ++mt) {
                int m0 = m_blk + wm * 64 + mt * 16 + kg * 4;
                int mp = (m0 & ~63) | keyperm(m0 & 63);   // sigma within 64-blk
                int bb = mp >> 11, ti = mp & 2047;
                ushort4 pk;
                pk.x = f32_to_bf16((acc[mt][nt][0] + bn) * oscale);
                pk.y = f32_to_bf16((acc[mt][nt][1] + bn) * oscale);
                pk.z = f32_to_bf16((acc[mt][nt][2] + bn) * oscale);
                pk.w = f32_to_bf16((acc[mt][nt][3] + bn) * oscale);
                *(ushort4*)((unsigned short*)outp +
                    ((size_t)(bb * 16 + hh) * 64 + dki) * 2048 + ti) = pk;
            }
        }
    } else {
        // SWAPPED C/D: lane holds n = kg*4+r (consecutive), m = r16 fixed.
        #pragma unroll
        for (int nt = 0; nt < NT16; ++nt) {
            int n0 = n_blk + wn * (NT16 * 16) + nt * 16 + kg * 4;
            float4 bn4 = *(const float4*)(bias + n0);
            #pragma unroll
            for (int mt = 0; mt < 4; ++mt) {
                int m = m_blk + wm * 64 + mt * 16 + r16;
                if (MODE == 3) {
                    float4 st;
                    st.x = (acc[mt][nt][0] + bn4.x) * oscale;
                    st.y = (acc[mt][nt][1] + bn4.y) * oscale;
                    st.z = (acc[mt][nt][2] + bn4.z) * oscale;
                    st.w = (acc[mt][nt][3] + bn4.w) * oscale;
                    *(float4*)((float*)outp + (size_t)m * D_MODEL + n0) = st;
                } else {
                    ushort4 pk;
                    pk.x = f32_to_bf16((acc[mt][nt][0] + bn4.x) * oscale);
                    pk.y = f32_to_bf16((acc[mt][nt][1] + bn4.y) * oscale);
                    pk.z = f32_to_bf16((acc[mt][nt][2] + bn4.z) * oscale);
                    pk.w = f32_to_bf16((acc[mt][nt][3] + bn4.w) * oscale);
                    *(ushort4*)((unsigned short*)outp + (size_t)m * D_MODEL + n0) = pk;
                }
            }
        }
    }
}

__global__ __launch_bounds__(256) void gemm_qkv(
    const unsigned short* __restrict__ qb, const unsigned short* __restrict__ kb,
    const unsigned short* __restrict__ vb, const unsigned short* __restrict__ Wqb,
    const unsigned short* __restrict__ Wkb, const unsigned short* __restrict__ Wvb,
    const float* __restrict__ bq, const float* __restrict__ bk, const float* __restrict__ bv,
    unsigned short* __restrict__ Qhp, unsigned short* __restrict__ Khp,
    unsigned short* __restrict__ Vtp)
{
    __shared__ __align__(16) unsigned short As[3 * 128 * 32];   // 24 KB tbuf
    __shared__ __align__(16) unsigned short Ws[3 * 128 * 32];   // 24 KB tbuf
    // Bijective XCD swizzle (grid 8x32x3, nwg=768): contiguous 96-chunks/XCD.
    int flat = blockIdx.x + (blockIdx.y << 3) + (blockIdx.z << 8);
    int w = (flat & 7) * 96 + (flat >> 3);
    int bx = w & 7, by = (w >> 3) & 31, z = w >> 8;
    const unsigned short* A = (z == 0) ? qb : (z == 1) ? kb : vb;
    const unsigned short* W = (z == 0) ? Wqb : (z == 1) ? Wkb : Wvb;
    const float* bias = (z == 0) ? bq : (z == 1) ? bk : bv;
    // Q stored pre-scaled by log2(e)/sqrt(dk): attn computes exp2(s) direct.
    float osc = (z == 0) ? 0.18033688011112042f : 1.0f;
    if (z < 2)
        gemm_body<0, 4>(A, W, bias, (z == 0) ? (void*)Qhp : (void*)Khp, As, Ws,
                        bx, by, osc);
    else
        gemm_body<2, 4>(A, W, bias, (void*)Vtp, As, Ws, bx, by, 1.0f);
}

__global__ __launch_bounds__(256) void gemm_out(
    const unsigned short* __restrict__ ab, const unsigned short* __restrict__ Wob,
    const float* __restrict__ bo, float* __restrict__ outp)
{
    __shared__ __align__(16) unsigned short As[3 * 128 * 32];   // 24 KB tbuf
    __shared__ __align__(16) unsigned short Ws[3 * 128 * 32];   // 24 KB tbuf
    // 128-wide N tile: grid 8x32 = 256 blocks; bijective XCD swizzle
    // (32-chunks/XCD): A-panel (1 MB) + full Wo (2 MB) fit one L2.
    int flat = blockIdx.x + (blockIdx.y << 3);
    int w = (flat & 7) * 32 + (flat >> 3);
    int bx = w & 7, by = w >> 3;
    gemm_body<3, 4>(ab, Wob, bo, (void*)outp, As, Ws, bx, by, 1.0f);
}

// --------------------------- flash attention --------------------------------
// One 64-q chunk per block (4 waves x 16 q). qc map is LONGEST-FIRST and
// per-CU balanced: CU's resident quadruple {31-y0, 16+y0, 15-y0, y0} sums to
// 66 tiles, with the 25-32-tile blocks in the first dispatch octet (y 0-7)
// so the serial causal tail overlaps the bulk. K/V TRIPLE-buffered with raw
// s_barrier + counted vmcnt(4): stage(t+2) stays in flight across barriers
// (no per-tile drain). Register-resident P (S^T = mfma(K,Q)); V stored
// key-permuted so PV B-frags are single b128 reads. Q pre-scaled -> exp2
// direct; denominator on the matrix pipe (lacc = MFMA(pa, ones)).
__global__ __launch_bounds__(256) void attn_fwd(
    const unsigned short* __restrict__ Qh, const unsigned short* __restrict__ Kh,
    const unsigned short* __restrict__ Vt, const int* __restrict__ mask,
    const int* __restrict__ causal_p, unsigned short* __restrict__ attnout)
{
    __shared__ __align__(16) unsigned short Ks[3][64 * 64];   // [key][dk] swz
    __shared__ __align__(16) unsigned short Vs[3][64 * 64];   // [dk][kperm] swz
    __shared__ unsigned long long kmS[32];                    // per-tile key mask

    const int tid = threadIdx.x;
    const int lane = tid & 63, wave = tid >> 6;
    const int bh = blockIdx.x;
    const int y = blockIdx.y, y0 = y & 7, j4 = y >> 3;
    // longest-first, per-CU-balanced qc map (bijective over 0..31)
    const int qc = (j4 == 0) ? (31 - y0) : (j4 == 1) ? (16 + y0)
                 : (j4 == 2) ? (15 - y0) : y0;
    const int b = bh >> 4, h = bh & 15;
    const int causal = *causal_p;
    const int r16 = lane & 15, kg = lane >> 4;

    const int q0 = qc * 64 + wave * 16;

    const unsigned short* Qb = Qh + (size_t)b * T_ * D_MODEL + h * 64;
    const unsigned short* Kb = Kh + (size_t)b * T_ * D_MODEL + h * 64;
    const unsigned short* Vb = Vt + (size_t)bh * 64 * T_;
    const int* mb = mask + b * T_;

    // precompute per-tile 64-bit key masks into LDS (wave w: tiles w, w+4, ..)
    for (int t = wave; t < 32; t += 4) {
        unsigned long long m = __ballot(mb[t * 64 + lane] != 0);
        if (lane == 0) kmS[t] = m;
    }

    // Q fragments (B-operand for S^T: lane holds Q[q0+r16][kg*8+j])
    bf16x8 qf0 = *(const bf16x8*)(Qb + (size_t)(q0 + r16) * D_MODEL + kg * 8);
    bf16x8 qf1 = *(const bf16x8*)(Qb + (size_t)(q0 + r16) * D_MODEL + 32 + kg * 8);

    // all-ones B-frag for the denominator MFMA
    union { unsigned u[4]; bf16x8 v; } onef;
    onef.u[0] = onef.u[1] = onef.u[2] = onef.u[3] = 0x3f803f80u;

    f32x4 lacc = (f32x4){0, 0, 0, 0};    // denom: lacc[r] = l for q = kg*4+r
    f32x4 o[4];
    #pragma unroll
    for (int f = 0; f < 4; ++f) o[f] = (f32x4){0, 0, 0, 0};
    const int lim = wave * 16 + r16;          // causal limit on diagonal tile

    const int nT = causal ? (qc + 1) : 32;

    // hoisted staging addresses (tile t adds t*64 rows on K / t*64 cols on V)
    const unsigned short* Kp[2]; const unsigned short* Vp[2];
    char* Kl[2]; char* Vl[2];
    #pragma unroll
    for (int j = 0; j < 2; ++j) {
        int si = j * 256 + tid;
        int row = si >> 3, cg = (si & 7) ^ (row & 7);
        Kp[j] = Kb + (size_t)row * D_MODEL + cg * 8;
        Vp[j] = Vb + (size_t)row * T_ + cg * 8;
        Kl[j] = (char*)Ks[0] + (j * 256 + wave * 64) * 16;
        Vl[j] = (char*)Vs[0] + (j * 256 + wave * 64) * 16;
    }
    auto stage = [&](int buf, int t) {
        #pragma unroll
        for (int j = 0; j < 2; ++j) {
            gload_lds16(Kp[j] + ((size_t)t << 16), Kl[j] + buf * 8192);  // t*64*1024
            gload_lds16(Vp[j] + (t << 6),          Vl[j] + buf * 8192);  // t*64
        }
    };

    // prologue: tiles 0,1 staged; sync drains them + the kmS ds_writes
    stage(0, 0);
    stage(1, 1);
    __syncthreads();
    int cb = 0;                                  // compute buffer = t % 3
    for (int t = 0; t < nT; ++t) {
        // wait ONLY for stage(t); stage(t+1) stays in flight across the
        // barrier. Last iter: drain.
        if (t + 1 < nT) asm volatile("s_waitcnt vmcnt(4)" ::: "memory");
        else            asm volatile("s_waitcnt vmcnt(0)" ::: "memory");
        __builtin_amdgcn_s_barrier();            // raw: no compiler drain
        __builtin_amdgcn_sched_barrier(0);       // ds_reads must not hoist
        if (t + 2 < nT) {
            int sb = cb + 2; if (sb >= 3) sb -= 3;
            stage(sb, t + 2);                    // buf freed by compute(t-1)
        }
        const unsigned short* Kst = Ks[cb];
        const unsigned short* Vst = Vs[cb];
        const bool diag = causal && (t == qc);

        // key mask for this 64-key tile (wave-uniform, LDS broadcast)
        unsigned long long km = kmS[t];

        // ---- S^T = K Q^T ----
        f32x4 s[4];
        __builtin_amdgcn_s_setprio(1);
        #pragma unroll
        for (int c = 0; c < 4; ++c) {
            int key = c * 16 + r16;
            bf16x8 kf0 = *(const bf16x8*)(Kst + key * 64 + ((kg ^ (key & 7)) * 8));
            bf16x8 kf1 = *(const bf16x8*)(Kst + key * 64 + (((4 + kg) ^ (key & 7)) * 8));
            f32x4 z = (f32x4){0, 0, 0, 0};
            z = MFMA(kf0, qf0, z);
            z = MFMA(kf1, qf1, z);
            s[c] = z;
        }
        __builtin_amdgcn_s_setprio(0);

        // ---- exp2 (Q pre-scaled; masks only when needed; uniform branch) ----
        float pv[4][4];
        if (!diag && km == ~0ull) {
            #pragma unroll
            for (int c = 0; c < 4; ++c)
                #pragma unroll
                for (int r = 0; r < 4; ++r)
                    pv[c][r] = __builtin_amdgcn_exp2f(s[c][r]);
        } else {
            #pragma unroll
            for (int c = 0; c < 4; ++c) {
                unsigned mc = (unsigned)(km >> (c * 16));
                #pragma unroll
                for (int r = 0; r < 4; ++r) {
                    int kbit = kg * 4 + r;
                    bool ok = ((mc >> kbit) & 1) && (!diag || (c * 16 + kbit <= lim));
                    pv[c][r] = ok ? __builtin_amdgcn_exp2f(s[c][r]) : 0.f;
                }
            }
        }

        // ---- pack into bf16x8 PV A-operands (sigma order) ----
        union pk_t { unsigned u[4]; bf16x8 v; };
        pk_t pa[2];
        #pragma unroll
        for (int c = 0; c < 4; ++c) {
            int half = (c & 1) * 2;
            pa[c >> 1].u[half]     = f32_to_bf16_fast(pv[c][0]) | (f32_to_bf16_fast(pv[c][1]) << 16);
            pa[c >> 1].u[half + 1] = f32_to_bf16_fast(pv[c][2]) | (f32_to_bf16_fast(pv[c][3]) << 16);
        }

        // ---- O += P V; denom += P 1 (matrix pipe, layout-proof) ----
        __builtin_amdgcn_s_setprio(1);
        lacc = MFMA(pa[0].v, onef.v, lacc);
        lacc = MFMA(pa[1].v, onef.v, lacc);
        #pragma unroll
        for (int f = 0; f < 4; ++f) {
            int row = f * 16 + r16;     // dk row in Vs
            int rx = row & 7;
            #pragma unroll
            for (int cp = 0; cp < 2; ++cp) {
                int g = cp * 4 + kg;    // storage granule = MFMA k-granule
                bf16x8 vf = *(const bf16x8*)(Vst + row * 64 + ((g ^ rx) * 8));
                o[f] = MFMA(pa[cp].v, vf, o[f]);
            }
        }
        __builtin_amdgcn_s_setprio(0);
        cb = (cb == 2) ? 0 : cb + 1;
    }

    // ---- epilogue: normalize with lane-local denom, store [B,T,D] ----
    #pragma unroll
    for (int r = 0; r < 4; ++r) {
        float iv = (lacc[r] > 0.f) ? 1.0f / lacc[r] : 0.f;
        size_t base = ((size_t)(b * T_ + q0 + kg * 4 + r)) * D_MODEL + h * 64;
        #pragma unroll
        for (int f = 0; f < 4; ++f)
            attnout[base + f * 16 + r16] = f32_to_bf16(o[f][r] * iv);
    }
}

// --------------------------- launch -----------------------------------------
extern "C" void kernel_launch(void* const* d_in, const int* in_sizes, int n_in,
                              void* d_out, int out_size, void* d_ws, size_t ws_size,
                              hipStream_t stream) {
    const float* q  = (const float*)d_in[0];
    const float* k  = (const float*)d_in[1];
    const float* v  = (const float*)d_in[2];
    const float* Wq = (const float*)d_in[3];
    const float* bq = (const float*)d_in[4];
    const float* Wk = (const float*)d_in[5];
    const float* bk = (const float*)d_in[6];
    const float* Wv = (const float*)d_in[7];
    const float* bv = (const float*)d_in[8];
    const float* Wo = (const float*)d_in[9];
    const float* bo = (const float*)d_in[10];
    const int* mask   = (const int*)d_in[11];
    const int* causal = (const int*)d_in[12];

    const size_t SZ_TOK = (size_t)M_TOK * D_MODEL;   // 4M elems
    const size_t SZ_W   = (size_t)D_MODEL * D_MODEL; // 1M elems

    unsigned short* qb  = (unsigned short*)d_ws;
    unsigned short* kb  = qb  + SZ_TOK;
    unsigned short* vb  = kb  + SZ_TOK;
    unsigned short* Wqb = vb  + SZ_TOK;
    unsigned short* Wkb = Wqb + SZ_W;
    unsigned short* Wvb = Wkb + SZ_W;
    unsigned short* Wob = Wvb + SZ_W;
    unsigned short* Qhp = Wob + SZ_W;
    unsigned short* Khp = Qhp + SZ_TOK;
    unsigned short* Vtp = Khp + SZ_TOK;
    unsigned short* ab  = Vtp + SZ_TOK;              // 64 MB total

    cvt_all<<<16384, 256, 0, stream>>>(q, k, v, Wq, Wk, Wv, Wo, (ushort4*)qb);

    gemm_qkv<<<dim3(D_MODEL / 128, M_TOK / 128, 3), 256, 0, stream>>>(
        qb, kb, vb, Wqb, Wkb, Wvb, bq, bk, bv, Qhp, Khp, Vtp);

    attn_fwd<<<dim3(32, 32), 256, 0, stream>>>(Qhp, Khp, Vtp, mask, causal, ab);

    gemm_out<<<dim3(D_MODEL / 128, M_TOK / 128), 256, 0, stream>>>(ab, Wob, bo,
                                                                   (float*)d_out);
}

// Round 6
// 213.537 us; speedup vs baseline: 1.0583x; 1.0195x over previous
//
#include <hip/hip_runtime.h>
#include <cstdint>
#include <cstddef>

// ---------------------------------------------------------------------------
// MHA: out = softmax(causal(mask((XWq)(XWk)^T/8))) (XWv) Wo + biases
// B=2, T=2048, D=1024, H=16, dk=64. bf16 MFMA, fp32 accumulate.
// R13 (attn VALU issue diet #2; sync structure FROZEN from R12):
//   VALU audit: ~60 insts/tile/lane, of which ~16 are per-tile LDS address
//   adds (runtime cb) and ~40 are the manual bf16 pack. Fixes:
//   (1) tile body instantiated at compile-time CB via unroll-by-3 (+tail):
//       all ds_read addresses fold to base + offset:imm (48KB < 64KB range).
//   (2) P-pack via (__bf16) casts in a union -> compiler emits
//       v_cvt_pk_bf16_f32 (2 vals/inst, RNE) instead of add/shift/or chains.
//   R12 carried: K/V triple-buffer + raw s_barrier + counted vmcnt(4),
//   longest-first qc map, Q pre-scaled (exp2 direct), denom on matrix pipe,
//   setprio around MFMA clusters. GEMMs frozen at R9/R10 structure.
// ---------------------------------------------------------------------------

typedef __bf16 bf16x8 __attribute__((ext_vector_type(8)));
typedef float f32x4 __attribute__((ext_vector_type(4)));

#define MFMA(a, b, c) __builtin_amdgcn_mfma_f32_16x16x32_bf16((a), (b), (c), 0, 0, 0)

static constexpr int D_MODEL = 1024;
static constexpr int T_ = 2048;
static constexpr int M_TOK = 4096;   // B*T

__device__ __forceinline__ unsigned short f32_to_bf16(float f) {   // RNE
    union { float f; uint32_t u; } v; v.f = f;
    uint32_t u = v.u;
    uint32_t r = u + 0x7fffu + ((u >> 16) & 1u);
    return (unsigned short)(r >> 16);
}
// pack two f32 -> bf16x2 (low = a). Compiler emits v_cvt_pk_bf16_f32 (RNE).
__device__ __forceinline__ unsigned pk2(float a, float b) {
    union { __bf16 h[2]; unsigned u; } z;
    z.h[0] = (__bf16)a; z.h[1] = (__bf16)b;
    return z.u;
}

typedef __attribute__((address_space(1))) void* as1_ptr;
typedef __attribute__((address_space(3))) void* as3_ptr;
__device__ __forceinline__ void gload_lds16(const void* g, void* l) {
    // lane's 16B land at (wave-uniform l) + lane*16
    __builtin_amdgcn_global_load_lds((as1_ptr)(void*)g, (as3_ptr)l, 16, 0, 0);
}

// sigma: actual key (within 64) -> storage index matching PV MFMA k-slots.
__device__ __forceinline__ int keyperm(int k) {
    return (k & 32) | ((k & 12) << 1) | ((k & 16) >> 2) | (k & 3);
}

// --------------------------- fused fp32 -> bf16 convert ---------------------
// dst (float4 units): q[0,1M) k[1M,2M) v[2M,3M) Wq Wk Wv Wo [3M..4M)
__global__ __launch_bounds__(256) void cvt_all(
    const float* __restrict__ q, const float* __restrict__ k,
    const float* __restrict__ v, const float* __restrict__ wq,
    const float* __restrict__ wk, const float* __restrict__ wv,
    const float* __restrict__ wo, ushort4* __restrict__ dst) {
    int i = blockIdx.x * blockDim.x + threadIdx.x;
    constexpr int R = 1 << 20;        // 1M float4 per token tensor
    const float* s;
    int idx;
    if (i < 3 * R) {
        s = (i < R) ? q : (i < 2 * R) ? k : v;
        idx = i & (R - 1);
    } else {
        int j = i - 3 * R;
        int w = j >> 18;
        s = (w == 0) ? wq : (w == 1) ? wk : (w == 2) ? wv : wo;
        idx = j & ((1 << 18) - 1);
    }
    float4 f = ((const float4*)s)[idx];
    ushort4 o;
    o.x = (unsigned short)f32_to_bf16(f.x); o.y = (unsigned short)f32_to_bf16(f.y);
    o.z = (unsigned short)f32_to_bf16(f.z); o.w = (unsigned short)f32_to_bf16(f.w);
    dst[i] = o;
}

// --------------------------- GEMM: C = A @ W^T + bias -----------------------
// Tile 128 x (NT16*32), BK=32, 4 waves 2x2, global_load_lds(16B).
// Triple-buffered LDS, raw s_barrier + counted vmcnt(4): two stages always
// in flight; the barrier never drains the load queue (main loop).
// Granule swizzle: row has 4 16B-granules; physical g = logical ^ ((row>>1)&3)
// -> a wave's 64 b128 reads map bijectively onto 64 slots (2/bank, free).
// MODE 0: bf16 row-major [M][1024] (Q,K; SWAPPED epilogue -> ushort4 stores).
// MODE 2: bf16 [B][H][64][Tperm] (V; UNswapped, t sigma-permuted per 64-blk).
// MODE 3: f32 row-major [M][1024] (SWAPPED -> float4 stores).
// oscale: multiplies (acc + bias) -- used to pre-scale Q by log2(e)/sqrt(dk).
template<int MODE, int NT16>
__device__ __forceinline__ void gemm_body(
    const unsigned short* __restrict__ A, const unsigned short* __restrict__ W,
    const float* __restrict__ bias, void* __restrict__ outp,
    unsigned short* As, unsigned short* Ws, int bx, int by, float oscale)
{
    constexpr bool SWAP = (MODE != 2);
    constexpr int BKE = 32;                     // K elems per step
    constexpr int ASZ = 128 * BKE;              // ushorts per A buffer (8 KB)
    constexpr int WSZ = NT16 * 32 * BKE;        // ushorts per W buffer
    constexpr int AL = ASZ / (256 * 8);         // gloads/thread for A (=2)
    constexpr int WL = WSZ / (256 * 8);         // gloads/thread for W (=2 @NT16=4)
    constexpr int NKS = D_MODEL / BKE;          // 32
    const int tid = threadIdx.x;
    const int lane = tid & 63, wave = tid >> 6;
    const int wm = wave >> 1, wn = wave & 1;
    const int r16 = lane & 15, kg = lane >> 4;
    const int m_blk = by * 128, n_blk = bx * (NT16 * 32);

    // hoisted staging addresses: source pre-swizzled, LDS dest linear
    const unsigned short* Ap[AL]; unsigned short* Albase[AL];
    #pragma unroll
    for (int j = 0; j < AL; ++j) {
        int si = j * 256 + tid;
        int row = si >> 2, p = si & 3, g = p ^ ((row >> 1) & 3);
        Ap[j] = A + (size_t)(m_blk + row) * D_MODEL + g * 8;
        Albase[j] = As + (j * 256 + wave * 64) * 8;   // wave-uniform base
    }
    const unsigned short* Wp[WL]; unsigned short* Wlbase[WL];
    #pragma unroll
    for (int j = 0; j < WL; ++j) {
        int si = j * 256 + tid;
        int row = si >> 2, p = si & 3, g = p ^ ((row >> 1) & 3);
        Wp[j] = W + (size_t)(n_blk + row) * D_MODEL + g * 8;
        Wlbase[j] = Ws + (j * 256 + wave * 64) * 8;
    }

    // hoisted (loop-invariant) ds_read offsets
    int aoff[4], woff[NT16];
    #pragma unroll
    for (int mt = 0; mt < 4; ++mt) {
        int row = wm * 64 + mt * 16 + r16;
        aoff[mt] = row * BKE + ((kg ^ ((row >> 1) & 3)) * 8);
    }
    #pragma unroll
    for (int nt = 0; nt < NT16; ++nt) {
        int row = wn * (NT16 * 16) + nt * 16 + r16;
        woff[nt] = row * BKE + ((kg ^ ((row >> 1) & 3)) * 8);
    }

    f32x4 acc[4][NT16];
    #pragma unroll
    for (int mt = 0; mt < 4; ++mt)
        #pragma unroll
        for (int nt = 0; nt < NT16; ++nt) acc[mt][nt] = (f32x4){0, 0, 0, 0};

    auto stage = [&](int bb, int k0) {
        #pragma unroll
        for (int j = 0; j < AL; ++j)
            gload_lds16(Ap[j] + k0, Albase[j] + bb * ASZ);
        #pragma unroll
        for (int j = 0; j < WL; ++j)
            gload_lds16(Wp[j] + k0, Wlbase[j] + bb * WSZ);
    };

    // prologue: two stages in flight
    stage(0, 0);
    stage(1, BKE);
    int cb = 0;                                 // compute buffer = ks % 3
    for (int ks = 0; ks < NKS; ++ks) {
        // wait ONLY for stage(ks) (issued 2 steps ago); stage(ks+1) stays in
        // flight across the barrier. Last iter: drain.
        if (ks + 1 < NKS) asm volatile("s_waitcnt vmcnt(4)" ::: "memory");
        else              asm volatile("s_waitcnt vmcnt(0)" ::: "memory");
        __builtin_amdgcn_s_barrier();           // raw: no compiler vmcnt drain
        __builtin_amdgcn_sched_barrier(0);      // ds_reads must not hoist above
        if (ks + 2 < NKS) {
            int sb = cb + 2; if (sb >= 3) sb -= 3;
            stage(sb, (ks + 2) * BKE);          // buf freed by compute(ks-1)
        }
        const unsigned short* Asb = As + cb * ASZ;
        const unsigned short* Wsb = Ws + cb * WSZ;
        bf16x8 af[4], wf[NT16];
        #pragma unroll
        for (int mt = 0; mt < 4; ++mt)
            af[mt] = *(const bf16x8*)(Asb + aoff[mt]);
        #pragma unroll
        for (int nt = 0; nt < NT16; ++nt)
            wf[nt] = *(const bf16x8*)(Wsb + woff[nt]);
        #pragma unroll
        for (int mt = 0; mt < 4; ++mt)
            #pragma unroll
            for (int nt = 0; nt < NT16; ++nt)
                acc[mt][nt] = SWAP ? MFMA(wf[nt], af[mt], acc[mt][nt])
                                   : MFMA(af[mt], wf[nt], acc[mt][nt]);
        cb = (cb == 2) ? 0 : cb + 1;
    }

    if (MODE == 2) {
        // UNswapped C/D: lane holds m = kg*4+r (t, consecutive), n = r16 fixed.
        #pragma unroll
        for (int nt = 0; nt < NT16; ++nt) {
            int n = n_blk + wn * (NT16 * 16) + nt * 16 + r16;
            float bn = bias[n];
            int hh = n >> 6, dki = n & 63;
            #pragma unroll
            for (int mt = 0; mt < 4; ++mt) {
                int m0 = m_blk + wm * 64 + mt * 16 + kg * 4;
                int mp = (m0 & ~63) | keyperm(m0 & 63);   // sigma within 64-blk
                int bb = mp >> 11, ti = mp & 2047;
                ushort4 pk;
                pk.x = f32_to_bf16((acc[mt][nt][0] + bn) * oscale);
                pk.y = f32_to_bf16((acc[mt][nt][1] + bn) * oscale);
                pk.z = f32_to_bf16((acc[mt][nt][2] + bn) * oscale);
                pk.w = f32_to_bf16((acc[mt][nt][3] + bn) * oscale);
                *(ushort4*)((unsigned short*)outp +
                    ((size_t)(bb * 16 + hh) * 64 + dki) * 2048 + ti) = pk;
            }
        }
    } else {
        // SWAPPED C/D: lane holds n = kg*4+r (consecutive), m = r16 fixed.
        #pragma unroll
        for (int nt = 0; nt < NT16; ++nt) {
            int n0 = n_blk + wn * (NT16 * 16) + nt * 16 + kg * 4;
            float4 bn4 = *(const float4*)(bias + n0);
            #pragma unroll
            for (int mt = 0; mt < 4; ++mt) {
                int m = m_blk + wm * 64 + mt * 16 + r16;
                if (MODE == 3) {
                    float4 st;
                    st.x = (acc[mt][nt][0] + bn4.x) * oscale;
                    st.y = (acc[mt][nt][1] + bn4.y) * oscale;
                    st.z = (acc[mt][nt][2] + bn4.z) * oscale;
                    st.w = (acc[mt][nt][3] + bn4.w) * oscale;
                    *(float4*)((float*)outp + (size_t)m * D_MODEL + n0) = st;
                } else {
                    ushort4 pk;
                    pk.x = f32_to_bf16((acc[mt][nt][0] + bn4.x) * oscale);
                    pk.y = f32_to_bf16((acc[mt][nt][1] + bn4.y) * oscale);
                    pk.z = f32_to_bf16((acc[mt][nt][2] + bn4.z) * oscale);
                    pk.w = f32_to_bf16((acc[mt][nt][3] + bn4.w) * oscale);
                    *(ushort4*)((unsigned short*)outp + (size_t)m * D_MODEL + n0) = pk;
                }
            }
        }
    }
}

__global__ __launch_bounds__(256) void gemm_qkv(
    const unsigned short* __restrict__ qb, const unsigned short* __restrict__ kb,
    const unsigned short* __restrict__ vb, const unsigned short* __restrict__ Wqb,
    const unsigned short* __restrict__ Wkb, const unsigned short* __restrict__ Wvb,
    const float* __restrict__ bq, const float* __restrict__ bk, const float* __restrict__ bv,
    unsigned short* __restrict__ Qhp, unsigned short* __restrict__ Khp,
    unsigned short* __restrict__ Vtp)
{
    __shared__ __align__(16) unsigned short As[3 * 128 * 32];   // 24 KB tbuf
    __shared__ __align__(16) unsigned short Ws[3 * 128 * 32];   // 24 KB tbuf
    // Bijective XCD swizzle (grid 8x32x3, nwg=768): contiguous 96-chunks/XCD.
    int flat = blockIdx.x + (blockIdx.y << 3) + (blockIdx.z << 8);
    int w = (flat & 7) * 96 + (flat >> 3);
    int bx = w & 7, by = (w >> 3) & 31, z = w >> 8;
    const unsigned short* A = (z == 0) ? qb : (z == 1) ? kb : vb;
    const unsigned short* W = (z == 0) ? Wqb : (z == 1) ? Wkb : Wvb;
    const float* bias = (z == 0) ? bq : (z == 1) ? bk : bv;
    // Q stored pre-scaled by log2(e)/sqrt(dk): attn computes exp2(s) direct.
    float osc = (z == 0) ? 0.18033688011112042f : 1.0f;
    if (z < 2)
        gemm_body<0, 4>(A, W, bias, (z == 0) ? (void*)Qhp : (void*)Khp, As, Ws,
                        bx, by, osc);
    else
        gemm_body<2, 4>(A, W, bias, (void*)Vtp, As, Ws, bx, by, 1.0f);
}

__global__ __launch_bounds__(256) void gemm_out(
    const unsigned short* __restrict__ ab, const unsigned short* __restrict__ Wob,
    const float* __restrict__ bo, float* __restrict__ outp)
{
    __shared__ __align__(16) unsigned short As[3 * 128 * 32];   // 24 KB tbuf
    __shared__ __align__(16) unsigned short Ws[3 * 128 * 32];   // 24 KB tbuf
    // 128-wide N tile: grid 8x32 = 256 blocks; bijective XCD swizzle
    // (32-chunks/XCD): A-panel (1 MB) + full Wo (2 MB) fit one L2.
    int flat = blockIdx.x + (blockIdx.y << 3);
    int w = (flat & 7) * 32 + (flat >> 3);
    int bx = w & 7, by = w >> 3;
    gemm_body<3, 4>(ab, Wob, bo, (void*)outp, As, Ws, bx, by, 1.0f);
}

// --------------------------- flash attention --------------------------------
// One 64-q chunk per block (4 waves x 16 q). Longest-first per-CU-balanced qc
// map; K/V TRIPLE-buffered, raw s_barrier + counted vmcnt(4). Tile body
// instantiated with COMPILE-TIME buffer index (unroll-by-3 + tail): all LDS
// reads become base + offset:imm, no per-tile address VALU. P-pack via
// (__bf16) casts -> v_cvt_pk_bf16_f32. Q pre-scaled -> exp2 direct; denom on
// the matrix pipe (lacc = MFMA(pa, ones)); setprio around MFMA clusters.
__global__ __launch_bounds__(256) void attn_fwd(
    const unsigned short* __restrict__ Qh, const unsigned short* __restrict__ Kh,
    const unsigned short* __restrict__ Vt, const int* __restrict__ mask,
    const int* __restrict__ causal_p, unsigned short* __restrict__ attnout)
{
    __shared__ __align__(16) unsigned short Ks[3][64 * 64];   // [key][dk] swz
    __shared__ __align__(16) unsigned short Vs[3][64 * 64];   // [dk][kperm] swz
    __shared__ unsigned long long kmS[32];                    // per-tile key mask

    const int tid = threadIdx.x;
    const int lane = tid & 63, wave = tid >> 6;
    const int bh = blockIdx.x;
    const int y = blockIdx.y, y0 = y & 7, j4 = y >> 3;
    // longest-first, per-CU-balanced qc map (bijective over 0..31)
    const int qc = (j4 == 0) ? (31 - y0) : (j4 == 1) ? (16 + y0)
                 : (j4 == 2) ? (15 - y0) : y0;
    const int b = bh >> 4, h = bh & 15;
    const int causal = *causal_p;
    const int r16 = lane & 15, kg = lane >> 4;

    const int q0 = qc * 64 + wave * 16;

    const unsigned short* Qb = Qh + (size_t)b * T_ * D_MODEL + h * 64;
    const unsigned short* Kb = Kh + (size_t)b * T_ * D_MODEL + h * 64;
    const unsigned short* Vb = Vt + (size_t)bh * 64 * T_;
    const int* mb = mask + b * T_;

    // precompute per-tile 64-bit key masks into LDS (wave w: tiles w, w+4, ..)
    for (int t = wave; t < 32; t += 4) {
        unsigned long long m = __ballot(mb[t * 64 + lane] != 0);
        if (lane == 0) kmS[t] = m;
    }

    // Q fragments (B-operand for S^T: lane holds Q[q0+r16][kg*8+j])
    bf16x8 qf0 = *(const bf16x8*)(Qb + (size_t)(q0 + r16) * D_MODEL + kg * 8);
    bf16x8 qf1 = *(const bf16x8*)(Qb + (size_t)(q0 + r16) * D_MODEL + 32 + kg * 8);

    // all-ones B-frag for the denominator MFMA
    union { unsigned u[4]; bf16x8 v; } onef;
    onef.u[0] = onef.u[1] = onef.u[2] = onef.u[3] = 0x3f803f80u;

    f32x4 lacc = (f32x4){0, 0, 0, 0};    // denom: lacc[r] = l for q = kg*4+r
    f32x4 o[4];
    #pragma unroll
    for (int f = 0; f < 4; ++f) o[f] = (f32x4){0, 0, 0, 0};
    const int lim = wave * 16 + r16;          // causal limit on diagonal tile

    const int nT = causal ? (qc + 1) : 32;

    // hoisted staging addresses (tile t adds t*64 rows on K / t*64 cols on V)
    const unsigned short* Kp[2]; const unsigned short* Vp[2];
    char* Kl[2]; char* Vl[2];
    #pragma unroll
    for (int j = 0; j < 2; ++j) {
        int si = j * 256 + tid;
        int row = si >> 3, cg = (si & 7) ^ (row & 7);
        Kp[j] = Kb + (size_t)row * D_MODEL + cg * 8;
        Vp[j] = Vb + (size_t)row * T_ + cg * 8;
        Kl[j] = (char*)Ks[0] + (j * 256 + wave * 64) * 16;
        Vl[j] = (char*)Vs[0] + (j * 256 + wave * 64) * 16;
    }
    auto stage = [&](int buf, int t) {
        #pragma unroll
        for (int j = 0; j < 2; ++j) {
            gload_lds16(Kp[j] + ((size_t)t << 16), Kl[j] + buf * 8192);  // t*64*1024
            gload_lds16(Vp[j] + (t << 6),          Vl[j] + buf * 8192);  // t*64
        }
    };

    // one tile iteration with COMPILE-TIME buffer index CB (t%3 == CB).
#define TILE_ITER(CB)                                                          \
    {                                                                          \
        if (t + 1 < nT) asm volatile("s_waitcnt vmcnt(4)" ::: "memory");       \
        else            asm volatile("s_waitcnt vmcnt(0)" ::: "memory");       \
        __builtin_amdgcn_s_barrier();                                          \
        __builtin_amdgcn_sched_barrier(0);                                     \
        if (t + 2 < nT) stage((CB + 2) % 3, t + 2);                            \
        const unsigned short* Kst = Ks[CB];                                    \
        const unsigned short* Vst = Vs[CB];                                    \
        const bool diag = causal && (t == qc);                                 \
        unsigned long long km = kmS[t];                                        \
        f32x4 s[4];                                                            \
        __builtin_amdgcn_s_setprio(1);                                         \
        _Pragma("unroll")                                                      \
        for (int c = 0; c < 4; ++c) {                                          \
            int key = c * 16 + r16;                                            \
            bf16x8 kf0 = *(const bf16x8*)(Kst + key * 64 + ((kg ^ (key & 7)) * 8));       \
            bf16x8 kf1 = *(const bf16x8*)(Kst + key * 64 + (((4 + kg) ^ (key & 7)) * 8)); \
            f32x4 z = (f32x4){0, 0, 0, 0};                                     \
            z = MFMA(kf0, qf0, z);                                             \
            z = MFMA(kf1, qf1, z);                                             \
            s[c] = z;                                                          \
        }                                                                      \
        __builtin_amdgcn_s_setprio(0);                                         \
        float pv[4][4];                                                        \
        if (!diag && km == ~0ull) {                                            \
            _Pragma("unroll")                                                  \
            for (int c = 0; c < 4; ++c)                                        \
                _Pragma("unroll")                                              \
                for (int r = 0; r < 4; ++r)                                    \
                    pv[c][r] = __builtin_amdgcn_exp2f(s[c][r]);                \
        } else {                                                               \
            _Pragma("unroll")                                                  \
            for (int c = 0; c < 4; ++c) {                                      \
                unsigned mc = (unsigned)(km >> (c * 16));                      \
                _Pragma("unroll")                                              \
                for (int r = 0; r < 4; ++r) {                                  \
                    int kbit = kg * 4 + r;                                     \
                    bool ok = ((mc >> kbit) & 1) && (!diag || (c * 16 + kbit <= lim)); \
                    pv[c][r] = ok ? __builtin_amdgcn_exp2f(s[c][r]) : 0.f;     \
                }                                                              \
            }                                                                  \
        }                                                                      \
        union pk_t { unsigned u[4]; bf16x8 v; };                               \
        pk_t pa[2];                                                            \
        _Pragma("unroll")                                                      \
        for (int c = 0; c < 4; ++c) {                                          \
            int half = (c & 1) * 2;                                            \
            pa[c >> 1].u[half]     = pk2(pv[c][0], pv[c][1]);                  \
            pa[c >> 1].u[half + 1] = pk2(pv[c][2], pv[c][3]);                  \
        }                                                                      \
        __builtin_amdgcn_s_setprio(1);                                         \
        lacc = MFMA(pa[0].v, onef.v, lacc);                                    \
        lacc = MFMA(pa[1].v, onef.v, lacc);                                    \
        _Pragma("unroll")                                                      \
        for (int f = 0; f < 4; ++f) {                                          \
            int row = f * 16 + r16;                                            \
            int rx = row & 7;                                                  \
            _Pragma("unroll")                                                  \
            for (int cp = 0; cp < 2; ++cp) {                                   \
                int g = cp * 4 + kg;                                           \
                bf16x8 vf = *(const bf16x8*)(Vst + row * 64 + ((g ^ rx) * 8)); \
                o[f] = MFMA(pa[cp].v, vf, o[f]);                               \
            }                                                                  \
        }                                                                      \
        __builtin_amdgcn_s_setprio(0);                                         \
    }

    // prologue: tiles 0,1 staged; sync drains them + the kmS ds_writes
    stage(0, 0);
    stage(1, 1);
    __syncthreads();
    int t = 0;
    while (t + 3 <= nT) {           // main: unrolled triples, CB compile-time
        TILE_ITER(0); ++t;
        TILE_ITER(1); ++t;
        TILE_ITER(2); ++t;
    }
    if (t < nT) { TILE_ITER(0); ++t; }      // tail (t multiple of 3 here)
    if (t < nT) { TILE_ITER(1); ++t; }
#undef TILE_ITER

    // ---- epilogue: normalize with lane-local denom, store [B,T,D] ----
    #pragma unroll
    for (int r = 0; r < 4; ++r) {
        float iv = (lacc[r] > 0.f) ? 1.0f / lacc[r] : 0.f;
        size_t base = ((size_t)(b * T_ + q0 + kg * 4 + r)) * D_MODEL + h * 64;
        #pragma unroll
        for (int f = 0; f < 4; ++f)
            attnout[base + f * 16 + r16] = f32_to_bf16(o[f][r] * iv);
    }
}

// --------------------------- launch -----------------------------------------
extern "C" void kernel_launch(void* const* d_in, const int* in_sizes, int n_in,
                              void* d_out, int out_size, void* d_ws, size_t ws_size,
                              hipStream_t stream) {
    const float* q  = (const float*)d_in[0];
    const float* k  = (const float*)d_in[1];
    const float* v  = (const float*)d_in[2];
    const float* Wq = (const float*)d_in[3];
    const float* bq = (const float*)d_in[4];
    const float* Wk = (const float*)d_in[5];
    const float* bk = (const float*)d_in[6];
    const float* Wv = (const float*)d_in[7];
    const float* bv = (const float*)d_in[8];
    const float* Wo = (const float*)d_in[9];
    const float* bo = (const float*)d_in[10];
    const int* mask   = (const int*)d_in[11];
    const int* causal = (const int*)d_in[12];

    const size_t SZ_TOK = (size_t)M_TOK * D_MODEL;   // 4M elems
    const size_t SZ_W   = (size_t)D_MODEL * D_MODEL; // 1M elems

    unsigned short* qb  = (unsigned short*)d_ws;
    unsigned short* kb  = qb  + SZ_TOK;
    unsigned short* vb  = kb  + SZ_TOK;
    unsigned short* Wqb = vb  + SZ_TOK;
    unsigned short* Wkb = Wqb + SZ_W;
    unsigned short* Wvb = Wkb + SZ_W;
    unsigned short* Wob = Wvb + SZ_W;
    unsigned short* Qhp = Wob + SZ_W;
    unsigned short* Khp = Qhp + SZ_TOK;
    unsigned short* Vtp = Khp + SZ_TOK;
    unsigned short* ab  = Vtp + SZ_TOK;              // 64 MB total

    cvt_all<<<16384, 256, 0, stream>>>(q, k, v, Wq, Wk, Wv, Wo, (ushort4*)qb);

    gemm_qkv<<<dim3(D_MODEL / 128, M_TOK / 128, 3), 256, 0, stream>>>(
        qb, kb, vb, Wqb, Wkb, Wvb, bq, bk, bv, Qhp, Khp, Vtp);

    attn_fwd<<<dim3(32, 32), 256, 0, stream>>>(Qhp, Khp, Vtp, mask, causal, ab);

    gemm_out<<<dim3(D_MODEL / 128, M_TOK / 128), 256, 0, stream>>>(ab, Wob, bo,
                                                                   (float*)d_out);
}